// Round 4
// baseline (1099.302 us; speedup 1.0000x reference)
//
#include <hip/hip_runtime.h>

#define N_NODES 100000
#define N_EDGES 1600000
// D_IN=128, D_HID=256, D_OUT=128

typedef float v4f __attribute__((ext_vector_type(4)));
typedef __bf16 v8bf __attribute__((ext_vector_type(8)));
typedef __bf16 v4bf __attribute__((ext_vector_type(4)));
typedef unsigned int v4u __attribute__((ext_vector_type(4)));

union FragU { v4u u; v8bf b; };
union PkU { unsigned int u; __bf16 h[2]; };

__device__ __forceinline__ int clampN(int v) {
    return v < 0 ? 0 : (v >= N_NODES ? N_NODES - 1 : v);
}
__device__ __forceinline__ float bfhi(unsigned int u) { return __uint_as_float(u & 0xffff0000u); }
__device__ __forceinline__ float bflo(unsigned int u) { return __uint_as_float(u << 16); }

// ---------------- CSR build ----------------
__global__ __launch_bounds__(256) void k_deg(
    const int* __restrict__ dst, int* __restrict__ deg)
{
    int e = blockIdx.x * 256 + threadIdx.x;
    if (e >= N_EDGES) return;
    atomicAdd(&deg[clampN(dst[e])], 1);
}

__global__ __launch_bounds__(1024) void k_scan(
    const int* __restrict__ deg, int* __restrict__ row_ptr)
{
    __shared__ int ps[1024];
    const int t = threadIdx.x;
    const int chunk = (N_NODES + 1023) / 1024;
    int lo = t * chunk;
    int hi = lo + chunk; if (hi > N_NODES) hi = N_NODES;
    int sum = 0;
    for (int i = lo; i < hi; ++i) sum += deg[i];
    ps[t] = sum;
    __syncthreads();
    for (int off = 1; off < 1024; off <<= 1) {
        int v = ps[t];
        int add = (t >= off) ? ps[t - off] : 0;
        __syncthreads();
        ps[t] = v + add;
        __syncthreads();
    }
    int run = (t > 0) ? ps[t - 1] : 0;
    for (int i = lo; i < hi; ++i) { row_ptr[i] = run; run += deg[i]; }
    if (t == 1023) row_ptr[N_NODES] = ps[1023];
}

__global__ __launch_bounds__(256) void k_fill(
    const int* __restrict__ src, const int* __restrict__ dst,
    const int* __restrict__ row_ptr, int* __restrict__ cursor,
    int* __restrict__ edge_src)
{
    int e = blockIdx.x * 256 + threadIdx.x;
    if (e >= N_EDGES) return;
    int s = clampN(src[e]);
    int d = clampN(dst[e]);
    int pos = atomicAdd(&cursor[d], 1);
    edge_src[row_ptr[d] + pos] = s;
}

// ---------------- dtype prep ----------------
__global__ __launch_bounds__(256) void k_cvt_x(
    const float* __restrict__ x, __bf16* __restrict__ xb, int n4)
{
    int t = blockIdx.x * 256 + threadIdx.x;
    if (t >= n4) return;
    float4 v = ((const float4*)x)[t];
    v4bf o = { (__bf16)v.x, (__bf16)v.y, (__bf16)v.z, (__bf16)v.w };
    *(v4bf*)(xb + (size_t)t * 4) = o;
}

// pack W [K][N] fp32 -> MFMA b-frag order: frag fi=(kc*NT+nt), lane l, elem j:
//   Wp[(fi*64+l)*8+j] = bf16(W[kc*32+(l>>4)*8+j][nt*16+(l&15)])
__global__ __launch_bounds__(256) void k_pack_w(
    const float* __restrict__ W, __bf16* __restrict__ Wp, int K, int N)
{
    int t = blockIdx.x * 256 + threadIdx.x;
    int NT = N >> 4;
    int total = (K >> 5) * NT * 64;
    if (t >= total) return;
    int l = t & 63;
    int fi = t >> 6;
    int kc = fi / NT, nt = fi % NT;
    int k0 = kc * 32 + (l >> 4) * 8;
    int col = nt * 16 + (l & 15);
    v8bf o;
    #pragma unroll
    for (int j = 0; j < 8; ++j) o[j] = (__bf16)W[(size_t)(k0 + j) * N + col];
    *(v8bf*)(Wp + (size_t)t * 8) = o;
}

// ---------------- CSR mean-gather: one wave per node, 4 edges in flight ----------------
// 16 lanes x 16B per edge row; slot = lane>>4 walks edges with stride 4.
// MODE 0: write bf16 mean row.  MODE 1: add fp32 mean row into outp.
template<int MODE>
__global__ __launch_bounds__(256) void k_gather16(
    const int* __restrict__ rp, const int* __restrict__ es,
    const __bf16* __restrict__ tab, void* __restrict__ outp)
{
    int wid = (blockIdx.x * 256 + threadIdx.x) >> 6;
    int l = threadIdx.x & 63;
    if (wid >= N_NODES) return;
    int start = rp[wid], end = rp[wid + 1];
    const int slot = l >> 4, c = l & 15;
    float s0 = 0.f, s1 = 0.f, s2 = 0.f, s3 = 0.f;
    float s4 = 0.f, s5 = 0.f, s6 = 0.f, s7 = 0.f;
    for (int e = start + slot; e < end; e += 4) {
        int sidx = es[e];
        v4u u = *(const v4u*)(tab + (size_t)sidx * 128 + c * 8);
        s0 += bflo(u.x); s1 += bfhi(u.x);
        s2 += bflo(u.y); s3 += bfhi(u.y);
        s4 += bflo(u.z); s5 += bfhi(u.z);
        s6 += bflo(u.w); s7 += bfhi(u.w);
    }
    // reduce the 4 slot-groups (lanes c, c+16, c+32, c+48)
    s0 += __shfl_xor(s0, 16); s1 += __shfl_xor(s1, 16);
    s2 += __shfl_xor(s2, 16); s3 += __shfl_xor(s3, 16);
    s4 += __shfl_xor(s4, 16); s5 += __shfl_xor(s5, 16);
    s6 += __shfl_xor(s6, 16); s7 += __shfl_xor(s7, 16);
    s0 += __shfl_xor(s0, 32); s1 += __shfl_xor(s1, 32);
    s2 += __shfl_xor(s2, 32); s3 += __shfl_xor(s3, 32);
    s4 += __shfl_xor(s4, 32); s5 += __shfl_xor(s5, 32);
    s6 += __shfl_xor(s6, 32); s7 += __shfl_xor(s7, 32);
    float invd = 1.f / fmaxf((float)(end - start), 1.f);
    if (slot == 0) {
        if (MODE == 0) {
            PkU a, b, cc, d;
            a.h[0] = (__bf16)(s0 * invd); a.h[1] = (__bf16)(s1 * invd);
            b.h[0] = (__bf16)(s2 * invd); b.h[1] = (__bf16)(s3 * invd);
            cc.h[0] = (__bf16)(s4 * invd); cc.h[1] = (__bf16)(s5 * invd);
            d.h[0] = (__bf16)(s6 * invd); d.h[1] = (__bf16)(s7 * invd);
            v4u o = { a.u, b.u, cc.u, d.u };
            ((v4u*)outp)[(size_t)wid * 16 + c] = o;
        } else {
            float4* o4 = (float4*)outp + (size_t)wid * 32 + c * 2;
            float4 va = o4[0], vb = o4[1];
            va.x += s0 * invd; va.y += s1 * invd; va.z += s2 * invd; va.w += s3 * invd;
            vb.x += s4 * invd; vb.y += s5 * invd; vb.z += s6 * invd; vb.w += s7 * invd;
            o4[0] = va; o4[1] = vb;
        }
    }
}

// ---------------- layer-1 GEMM: weights in LDS, persistent blocks ----------------
// h[n,0:256] = agg1[n]@Wl1 + x[n]@Wr1 + bl1 + p1[n]
// 512 thr = 8 waves; wave w owns 16 rows of each 128-row tile, all 256 cols.
__global__ __launch_bounds__(512) void k_g1(
    const __bf16* __restrict__ aggb, const __bf16* __restrict__ xb,
    const __bf16* __restrict__ Wl1p, const __bf16* __restrict__ Wr1p,
    const float* __restrict__ bl1, const float* __restrict__ p1,
    __bf16* __restrict__ hb)
{
    __shared__ char wl[65536];
    __shared__ char wr[65536];
    const int tid = threadIdx.x;
    {
        const v4u* gl = (const v4u*)Wl1p; v4u* sl = (v4u*)wl;
        const v4u* gr = (const v4u*)Wr1p; v4u* sr = (v4u*)wr;
        #pragma unroll
        for (int i = 0; i < 8; ++i) {
            sl[i * 512 + tid] = gl[i * 512 + tid];
            sr[i * 512 + tid] = gr[i * 512 + tid];
        }
    }
    const int w = tid >> 6, l = tid & 63;
    const int lrow = l & 15, kg = l >> 4;
    float blv[16];
    #pragma unroll
    for (int nt = 0; nt < 16; ++nt) blv[nt] = bl1[nt * 16 + lrow];
    __syncthreads();

    const v4f zf = {0.f, 0.f, 0.f, 0.f};
    for (int tile = blockIdx.x; tile * 128 < N_NODES; tile += gridDim.x) {
        int row0 = tile * 128 + w * 16;
        int arow = row0 + lrow; if (arow >= N_NODES) arow = N_NODES - 1;
        FragU ag[4], xv[4];
        #pragma unroll
        for (int kc = 0; kc < 4; ++kc) {
            size_t off = (size_t)arow * 128 + kc * 32 + kg * 8;
            ag[kc].u = *(const v4u*)(aggb + off);
            xv[kc].u = *(const v4u*)(xb + off);
        }
        v4f acc[16];
        #pragma unroll
        for (int nt = 0; nt < 16; ++nt) acc[nt] = zf;
        #pragma unroll
        for (int kc = 0; kc < 4; ++kc) {
            #pragma unroll
            for (int nt = 0; nt < 16; ++nt) {
                FragU bl_, br_;
                bl_.u = *(const v4u*)(wl + ((kc * 16 + nt) * 64 + l) * 16);
                br_.u = *(const v4u*)(wr + ((kc * 16 + nt) * 64 + l) * 16);
                acc[nt] = __builtin_amdgcn_mfma_f32_16x16x32_bf16(ag[kc].b, bl_.b, acc[nt], 0, 0, 0);
                acc[nt] = __builtin_amdgcn_mfma_f32_16x16x32_bf16(xv[kc].b, br_.b, acc[nt], 0, 0, 0);
            }
        }
        #pragma unroll
        for (int nt = 0; nt < 16; ++nt) {
            #pragma unroll
            for (int r = 0; r < 4; ++r) {
                int row = row0 + kg * 4 + r;
                if (row < N_NODES) {
                    int col = nt * 16 + lrow;
                    float hv = acc[nt][r] + blv[nt] + p1[(size_t)row * 256 + col];
                    hb[(size_t)row * 256 + col] = (__bf16)hv;
                }
            }
        }
    }
}

// ---------------- layer-2 GEMM: weights in LDS, persistent blocks ----------------
// t2[n] = h[n]@Wl2 ; out[n] = h[n]@Wr2 + bl2 + p2[n]
__global__ __launch_bounds__(512) void k_g2(
    const __bf16* __restrict__ hb,
    const __bf16* __restrict__ Wl2p, const __bf16* __restrict__ Wr2p,
    const float* __restrict__ bl2, const float* __restrict__ p2,
    __bf16* __restrict__ t2b, float* __restrict__ outp)
{
    __shared__ char wl[65536];
    __shared__ char wr[65536];
    const int tid = threadIdx.x;
    {
        const v4u* gl = (const v4u*)Wl2p; v4u* sl = (v4u*)wl;
        const v4u* gr = (const v4u*)Wr2p; v4u* sr = (v4u*)wr;
        #pragma unroll
        for (int i = 0; i < 8; ++i) {
            sl[i * 512 + tid] = gl[i * 512 + tid];
            sr[i * 512 + tid] = gr[i * 512 + tid];
        }
    }
    const int w = tid >> 6, l = tid & 63;
    const int lrow = l & 15, kg = l >> 4;
    float blv[8];
    #pragma unroll
    for (int nt = 0; nt < 8; ++nt) blv[nt] = bl2[nt * 16 + lrow];
    __syncthreads();

    const v4f zf = {0.f, 0.f, 0.f, 0.f};
    for (int tile = blockIdx.x; tile * 128 < N_NODES; tile += gridDim.x) {
        int row0 = tile * 128 + w * 16;
        int arow = row0 + lrow; if (arow >= N_NODES) arow = N_NODES - 1;
        FragU a[8];
        #pragma unroll
        for (int kc = 0; kc < 8; ++kc)
            a[kc].u = *(const v4u*)(hb + (size_t)arow * 256 + kc * 32 + kg * 8);
        v4f acct[8], acco[8];
        #pragma unroll
        for (int nt = 0; nt < 8; ++nt) { acct[nt] = zf; acco[nt] = zf; }
        #pragma unroll
        for (int kc = 0; kc < 8; ++kc) {
            #pragma unroll
            for (int nt = 0; nt < 8; ++nt) {
                FragU bl_, br_;
                bl_.u = *(const v4u*)(wl + ((kc * 8 + nt) * 64 + l) * 16);
                br_.u = *(const v4u*)(wr + ((kc * 8 + nt) * 64 + l) * 16);
                acct[nt] = __builtin_amdgcn_mfma_f32_16x16x32_bf16(a[kc].b, bl_.b, acct[nt], 0, 0, 0);
                acco[nt] = __builtin_amdgcn_mfma_f32_16x16x32_bf16(a[kc].b, br_.b, acco[nt], 0, 0, 0);
            }
        }
        #pragma unroll
        for (int nt = 0; nt < 8; ++nt) {
            #pragma unroll
            for (int r = 0; r < 4; ++r) {
                int row = row0 + kg * 4 + r;
                if (row < N_NODES) {
                    int col = nt * 16 + lrow;
                    t2b[(size_t)row * 128 + col] = (__bf16)acct[nt][r];
                    outp[(size_t)row * 128 + col] =
                        acco[nt][r] + blv[nt] + p2[(size_t)row * 128 + col];
                }
            }
        }
    }
}

extern "C" void kernel_launch(void* const* d_in, const int* in_sizes, int n_in,
                              void* d_out, int out_size, void* d_ws, size_t ws_size,
                              hipStream_t stream)
{
    const float* x   = (const float*)d_in[0];
    const int*   ei  = (const int*)d_in[1];
    const float* p1  = (const float*)d_in[2];
    const float* p2  = (const float*)d_in[3];
    const float* Wl1 = (const float*)d_in[4];
    const float* bl1 = (const float*)d_in[5];
    const float* Wr1 = (const float*)d_in[6];
    const float* Wl2 = (const float*)d_in[7];
    const float* bl2 = (const float*)d_in[8];
    const float* Wr2 = (const float*)d_in[9];
    const int* src = ei;
    const int* dst = ei + N_EDGES;

    char* wp = (char*)d_ws;
    __bf16* xb   = (__bf16*)wp; wp += (size_t)N_NODES * 128 * 2;
    __bf16* aggb = (__bf16*)wp; wp += (size_t)N_NODES * 128 * 2;
    __bf16* t2b  = (__bf16*)wp; wp += (size_t)N_NODES * 128 * 2;
    __bf16* hb   = (__bf16*)wp; wp += (size_t)N_NODES * 256 * 2;
    __bf16* Wl1p = (__bf16*)wp; wp += 128 * 256 * 2;
    __bf16* Wr1p = (__bf16*)wp; wp += 128 * 256 * 2;
    __bf16* Wl2p = (__bf16*)wp; wp += 256 * 128 * 2;
    __bf16* Wr2p = (__bf16*)wp; wp += 256 * 128 * 2;
    int* deg     = (int*)wp; wp += (size_t)N_NODES * 4;
    int* cursor  = (int*)wp; wp += (size_t)N_NODES * 4;
    int* rowp    = (int*)wp; wp += (size_t)(N_NODES + 1) * 4 + 12;
    int* es      = (int*)wp;

    hipMemsetAsync(deg,    0, (size_t)N_NODES * 4, stream);
    hipMemsetAsync(cursor, 0, (size_t)N_NODES * 4, stream);

    const int eblocks = (N_EDGES + 255) / 256;
    const int gblocks = (N_NODES * 64 + 255) / 256;
    const int n4 = N_NODES * 128 / 4;

    k_cvt_x<<<(n4 + 255) / 256, 256, 0, stream>>>(x, xb, n4);
    k_pack_w<<<16, 256, 0, stream>>>(Wl1, Wl1p, 128, 256);
    k_pack_w<<<16, 256, 0, stream>>>(Wr1, Wr1p, 128, 256);
    k_pack_w<<<16, 256, 0, stream>>>(Wl2, Wl2p, 256, 128);
    k_pack_w<<<16, 256, 0, stream>>>(Wr2, Wr2p, 256, 128);
    k_deg<<<eblocks, 256, 0, stream>>>(dst, deg);
    k_scan<<<1, 1024, 0, stream>>>(deg, rowp);
    k_fill<<<eblocks, 256, 0, stream>>>(src, dst, rowp, cursor, es);

    k_gather16<0><<<gblocks, 256, 0, stream>>>(rowp, es, xb, aggb);
    k_g1<<<256, 512, 0, stream>>>(aggb, xb, Wl1p, Wr1p, bl1, p1, hb);
    k_g2<<<256, 512, 0, stream>>>(hb, Wl2p, Wr2p, bl2, p2, t2b, (float*)d_out);
    k_gather16<1><<<gblocks, 256, 0, stream>>>(rowp, es, t2b, (void*)d_out);
}

// Round 5
// 674.337 us; speedup vs baseline: 1.6302x; 1.6302x over previous
//
#include <hip/hip_runtime.h>

#define N_NODES 100000
#define N_EDGES 1600000
// D_IN=128, D_HID=256, D_OUT=128

typedef float v4f __attribute__((ext_vector_type(4)));
typedef __bf16 v8bf __attribute__((ext_vector_type(8)));
typedef __bf16 v4bf __attribute__((ext_vector_type(4)));
typedef unsigned int v4u __attribute__((ext_vector_type(4)));

union FragU { v4u u; v8bf b; };
union PkU { unsigned int u; __bf16 h[2]; };

__device__ __forceinline__ int clampN(int v) {
    return v < 0 ? 0 : (v >= N_NODES ? N_NODES - 1 : v);
}
__device__ __forceinline__ float bfhi(unsigned int u) { return __uint_as_float(u & 0xffff0000u); }
__device__ __forceinline__ float bflo(unsigned int u) { return __uint_as_float(u << 16); }

// ---------------- CSR build ----------------
__global__ __launch_bounds__(256) void k_deg(
    const int* __restrict__ dst, int* __restrict__ deg)
{
    int e = blockIdx.x * 256 + threadIdx.x;
    if (e >= N_EDGES) return;
    atomicAdd(&deg[clampN(dst[e])], 1);
}

__global__ __launch_bounds__(1024) void k_scan(
    const int* __restrict__ deg, int* __restrict__ row_ptr)
{
    __shared__ int ps[1024];
    const int t = threadIdx.x;
    const int chunk = (N_NODES + 1023) / 1024;
    int lo = t * chunk;
    int hi = lo + chunk; if (hi > N_NODES) hi = N_NODES;
    int sum = 0;
    for (int i = lo; i < hi; ++i) sum += deg[i];
    ps[t] = sum;
    __syncthreads();
    for (int off = 1; off < 1024; off <<= 1) {
        int v = ps[t];
        int add = (t >= off) ? ps[t - off] : 0;
        __syncthreads();
        ps[t] = v + add;
        __syncthreads();
    }
    int run = (t > 0) ? ps[t - 1] : 0;
    for (int i = lo; i < hi; ++i) { row_ptr[i] = run; run += deg[i]; }
    if (t == 1023) row_ptr[N_NODES] = ps[1023];
}

__global__ __launch_bounds__(256) void k_fill(
    const int* __restrict__ src, const int* __restrict__ dst,
    const int* __restrict__ row_ptr, int* __restrict__ cursor,
    int* __restrict__ edge_src)
{
    int e = blockIdx.x * 256 + threadIdx.x;
    if (e >= N_EDGES) return;
    int s = clampN(src[e]);
    int d = clampN(dst[e]);
    int pos = atomicAdd(&cursor[d], 1);
    edge_src[row_ptr[d] + pos] = s;
}

// ---------------- dtype prep ----------------
__global__ __launch_bounds__(256) void k_cvt_x(
    const float* __restrict__ x, __bf16* __restrict__ xb, int n4)
{
    int t = blockIdx.x * 256 + threadIdx.x;
    if (t >= n4) return;
    float4 v = ((const float4*)x)[t];
    v4bf o = { (__bf16)v.x, (__bf16)v.y, (__bf16)v.z, (__bf16)v.w };
    *(v4bf*)(xb + (size_t)t * 4) = o;
}

// pack W [K][N] fp32 -> MFMA b-frag order: frag fi=(kc*NT+nt), lane l, elem j:
//   Wp[(fi*64+l)*8+j] = bf16(W[kc*32+(l>>4)*8+j][nt*16+(l&15)])
__global__ __launch_bounds__(256) void k_pack_w(
    const float* __restrict__ W, __bf16* __restrict__ Wp, int K, int N)
{
    int t = blockIdx.x * 256 + threadIdx.x;
    int NT = N >> 4;
    int total = (K >> 5) * NT * 64;
    if (t >= total) return;
    int l = t & 63;
    int fi = t >> 6;
    int kc = fi / NT, nt = fi % NT;
    int k0 = kc * 32 + (l >> 4) * 8;
    int col = nt * 16 + (l & 15);
    v8bf o;
    #pragma unroll
    for (int j = 0; j < 8; ++j) o[j] = (__bf16)W[(size_t)(k0 + j) * N + col];
    *(v8bf*)(Wp + (size_t)t * 8) = o;
}

// ---------------- CSR mean-gather: one wave per node, 4 edges in flight ----------------
// 16 lanes x 16B per edge row; slot = lane>>4 walks edges with stride 4.
// MODE 0: write bf16 mean row.  MODE 1: add fp32 mean row into outp.
template<int MODE>
__global__ __launch_bounds__(256) void k_gather16(
    const int* __restrict__ rp, const int* __restrict__ es,
    const __bf16* __restrict__ tab, void* __restrict__ outp)
{
    int wid = (blockIdx.x * 256 + threadIdx.x) >> 6;
    int l = threadIdx.x & 63;
    if (wid >= N_NODES) return;
    int start = rp[wid], end = rp[wid + 1];
    const int slot = l >> 4, c = l & 15;
    float s0 = 0.f, s1 = 0.f, s2 = 0.f, s3 = 0.f;
    float s4 = 0.f, s5 = 0.f, s6 = 0.f, s7 = 0.f;
    for (int e = start + slot; e < end; e += 4) {
        int sidx = es[e];
        v4u u = *(const v4u*)(tab + (size_t)sidx * 128 + c * 8);
        s0 += bflo(u.x); s1 += bfhi(u.x);
        s2 += bflo(u.y); s3 += bfhi(u.y);
        s4 += bflo(u.z); s5 += bfhi(u.z);
        s6 += bflo(u.w); s7 += bfhi(u.w);
    }
    s0 += __shfl_xor(s0, 16); s1 += __shfl_xor(s1, 16);
    s2 += __shfl_xor(s2, 16); s3 += __shfl_xor(s3, 16);
    s4 += __shfl_xor(s4, 16); s5 += __shfl_xor(s5, 16);
    s6 += __shfl_xor(s6, 16); s7 += __shfl_xor(s7, 16);
    s0 += __shfl_xor(s0, 32); s1 += __shfl_xor(s1, 32);
    s2 += __shfl_xor(s2, 32); s3 += __shfl_xor(s3, 32);
    s4 += __shfl_xor(s4, 32); s5 += __shfl_xor(s5, 32);
    s6 += __shfl_xor(s6, 32); s7 += __shfl_xor(s7, 32);
    float invd = 1.f / fmaxf((float)(end - start), 1.f);
    if (slot == 0) {
        if (MODE == 0) {
            PkU a, b, cc, d;
            a.h[0] = (__bf16)(s0 * invd); a.h[1] = (__bf16)(s1 * invd);
            b.h[0] = (__bf16)(s2 * invd); b.h[1] = (__bf16)(s3 * invd);
            cc.h[0] = (__bf16)(s4 * invd); cc.h[1] = (__bf16)(s5 * invd);
            d.h[0] = (__bf16)(s6 * invd); d.h[1] = (__bf16)(s7 * invd);
            v4u o = { a.u, b.u, cc.u, d.u };
            ((v4u*)outp)[(size_t)wid * 16 + c] = o;
        } else {
            float4* o4 = (float4*)outp + (size_t)wid * 32 + c * 2;
            float4 va = o4[0], vb = o4[1];
            va.x += s0 * invd; va.y += s1 * invd; va.z += s2 * invd; va.w += s3 * invd;
            vb.x += s4 * invd; vb.y += s5 * invd; vb.z += s6 * invd; vb.w += s7 * invd;
            o4[0] = va; o4[1] = vb;
        }
    }
}

// ---------------- fused MFMA: G1 (h) -> LDS -> G2 (t2 + out_partial) ----------------
// 256 thr = 4 waves (2x2), tile 64 rows. Weight B-frags register-double-buffered:
// each pipeline step issues 8 x 16B loads for step s+1, then 16 MFMAs of step s.
__global__ __launch_bounds__(256, 2) void k_fused(
    const __bf16* __restrict__ aggb, const __bf16* __restrict__ xb,
    const __bf16* __restrict__ Wl1p, const __bf16* __restrict__ Wr1p,
    const float* __restrict__ bl1, const float* __restrict__ p1,
    const __bf16* __restrict__ Wl2p, const __bf16* __restrict__ Wr2p,
    const float* __restrict__ bl2, const float* __restrict__ p2,
    __bf16* __restrict__ t2b, float* __restrict__ outp)
{
    __shared__ __bf16 hS[64 * 256];
    char* hB = (char*)hS;
    const int tid = threadIdx.x;
    const int l = tid & 63, w = tid >> 6;
    const int wr = w >> 1, wc = w & 1;
    const int brow = blockIdx.x * 64;
    const int lrow = l & 15, kg = l >> 4;
    const v4f zf = {0.f, 0.f, 0.f, 0.f};

    // ---- G1 ----
    v4f acc[2][8];
    #pragma unroll
    for (int i = 0; i < 2; ++i)
        #pragma unroll
        for (int j = 0; j < 8; ++j) acc[i][j] = zf;

    float blv1[8];
    #pragma unroll
    for (int nt = 0; nt < 8; ++nt) blv1[nt] = bl1[wc * 128 + nt * 16 + lrow];

    int arow[2];
    #pragma unroll
    for (int rb = 0; rb < 2; ++rb) {
        int r = brow + wr * 32 + rb * 16 + lrow;
        arow[rb] = r < N_NODES ? r : N_NODES - 1;
    }

    // A-fragments for all of K, upfront (32 VGPRs)
    FragU ag[4], xv[4];
    #pragma unroll
    for (int kc = 0; kc < 4; ++kc) {
        size_t off = (size_t)arow[0] * 128 + kc * 32 + kg * 8;
        ag[kc].u = *(const v4u*)(aggb + off);
        xv[kc].u = *(const v4u*)(xb + off);
    }
    FragU ag1[4], xv1[4];
    #pragma unroll
    for (int kc = 0; kc < 4; ++kc) {
        size_t off = (size_t)arow[1] * 128 + kc * 32 + kg * 8;
        ag1[kc].u = *(const v4u*)(aggb + off);
        xv1[kc].u = *(const v4u*)(xb + off);
    }

    // G1 pipeline: 8 steps, step s: kc=s>>1, nt-quad = (s&1). Dbuf frag quads.
    {
        FragU bwl[2][4], bwr[2][4];
        #pragma unroll
        for (int nt = 0; nt < 4; ++nt) {
            int ntg = wc * 8 + nt;                 // s=0: kc=0, half=0
            bwl[0][nt].u = *(const v4u*)(Wl1p + ((size_t)(0 * 16 + ntg) * 64 + l) * 8);
            bwr[0][nt].u = *(const v4u*)(Wr1p + ((size_t)(0 * 16 + ntg) * 64 + l) * 8);
        }
        #pragma unroll
        for (int s = 0; s < 8; ++s) {
            const int cur = s & 1, nxt = cur ^ 1;
            if (s < 7) {
                const int kcn = (s + 1) >> 1, halfn = (s + 1) & 1;
                #pragma unroll
                for (int nt = 0; nt < 4; ++nt) {
                    int ntg = wc * 8 + halfn * 4 + nt;
                    bwl[nxt][nt].u = *(const v4u*)(Wl1p + ((size_t)(kcn * 16 + ntg) * 64 + l) * 8);
                    bwr[nxt][nt].u = *(const v4u*)(Wr1p + ((size_t)(kcn * 16 + ntg) * 64 + l) * 8);
                }
            }
            const int kc = s >> 1, half = s & 1;
            #pragma unroll
            for (int nt = 0; nt < 4; ++nt) {
                const int ai = half * 4 + nt;
                acc[0][ai] = __builtin_amdgcn_mfma_f32_16x16x32_bf16(ag[kc].b,  bwl[cur][nt].b, acc[0][ai], 0, 0, 0);
                acc[1][ai] = __builtin_amdgcn_mfma_f32_16x16x32_bf16(ag1[kc].b, bwl[cur][nt].b, acc[1][ai], 0, 0, 0);
                acc[0][ai] = __builtin_amdgcn_mfma_f32_16x16x32_bf16(xv[kc].b,  bwr[cur][nt].b, acc[0][ai], 0, 0, 0);
                acc[1][ai] = __builtin_amdgcn_mfma_f32_16x16x32_bf16(xv1[kc].b, bwr[cur][nt].b, acc[1][ai], 0, 0, 0);
            }
        }
    }

    // ---- repack h (+bias+pert) into swizzled LDS ----
    #pragma unroll
    for (int rb = 0; rb < 2; ++rb)
        #pragma unroll
        for (int nt = 0; nt < 8; ++nt)
            #pragma unroll
            for (int r = 0; r < 4; ++r) {
                int row = wr * 32 + rb * 16 + kg * 4 + r;
                int grow = brow + row;
                int col = wc * 128 + nt * 16 + lrow;
                float hv = (rb ? acc[1][nt][r] : acc[0][nt][r]) + blv1[nt];
                if (grow < N_NODES) hv += p1[(size_t)grow * 256 + col];
                int byte = (row * 512 + col * 2) ^ ((row & 7) << 4);
                *(__bf16*)(hB + byte) = (__bf16)hv;
            }
    __syncthreads();

    // ---- G2 ----
    v4f acct[2][4], acco[2][4];
    #pragma unroll
    for (int i = 0; i < 2; ++i)
        #pragma unroll
        for (int j = 0; j < 4; ++j) { acct[i][j] = zf; acco[i][j] = zf; }

    float blv2[4];
    #pragma unroll
    for (int nt = 0; nt < 4; ++nt) blv2[nt] = bl2[wc * 64 + nt * 16 + lrow];

    {
        FragU bwl[2][4], bwr[2][4];
        #pragma unroll
        for (int nt = 0; nt < 4; ++nt) {
            int ntg = wc * 4 + nt;                 // kc = 0
            bwl[0][nt].u = *(const v4u*)(Wl2p + ((size_t)(0 * 8 + ntg) * 64 + l) * 8);
            bwr[0][nt].u = *(const v4u*)(Wr2p + ((size_t)(0 * 8 + ntg) * 64 + l) * 8);
        }
        #pragma unroll
        for (int kc = 0; kc < 8; ++kc) {
            const int cur = kc & 1, nxt = cur ^ 1;
            if (kc < 7) {
                #pragma unroll
                for (int nt = 0; nt < 4; ++nt) {
                    int ntg = wc * 4 + nt;
                    bwl[nxt][nt].u = *(const v4u*)(Wl2p + ((size_t)((kc + 1) * 8 + ntg) * 64 + l) * 8);
                    bwr[nxt][nt].u = *(const v4u*)(Wr2p + ((size_t)((kc + 1) * 8 + ntg) * 64 + l) * 8);
                }
            }
            FragU a0, a1;
            {
                int row = wr * 32 + 0 * 16 + lrow;
                int byte = (row * 512 + kc * 64 + kg * 16) ^ ((row & 7) << 4);
                a0.u = *(const v4u*)(hB + byte);
                row = wr * 32 + 1 * 16 + lrow;
                byte = (row * 512 + kc * 64 + kg * 16) ^ ((row & 7) << 4);
                a1.u = *(const v4u*)(hB + byte);
            }
            #pragma unroll
            for (int nt = 0; nt < 4; ++nt) {
                acct[0][nt] = __builtin_amdgcn_mfma_f32_16x16x32_bf16(a0.b, bwl[cur][nt].b, acct[0][nt], 0, 0, 0);
                acct[1][nt] = __builtin_amdgcn_mfma_f32_16x16x32_bf16(a1.b, bwl[cur][nt].b, acct[1][nt], 0, 0, 0);
                acco[0][nt] = __builtin_amdgcn_mfma_f32_16x16x32_bf16(a0.b, bwr[cur][nt].b, acco[0][nt], 0, 0, 0);
                acco[1][nt] = __builtin_amdgcn_mfma_f32_16x16x32_bf16(a1.b, bwr[cur][nt].b, acco[1][nt], 0, 0, 0);
            }
        }
    }

    #pragma unroll
    for (int rb = 0; rb < 2; ++rb)
        #pragma unroll
        for (int nt = 0; nt < 4; ++nt)
            #pragma unroll
            for (int r = 0; r < 4; ++r) {
                int row = wr * 32 + rb * 16 + kg * 4 + r;
                int grow = brow + row;
                if (grow >= N_NODES) continue;
                int col = wc * 64 + nt * 16 + lrow;
                float tv = rb ? acct[1][nt][r] : acct[0][nt][r];
                float ov = rb ? acco[1][nt][r] : acco[0][nt][r];
                t2b[(size_t)grow * 128 + col] = (__bf16)tv;
                outp[(size_t)grow * 128 + col] =
                    ov + blv2[nt] + p2[(size_t)grow * 128 + col];
            }
}

extern "C" void kernel_launch(void* const* d_in, const int* in_sizes, int n_in,
                              void* d_out, int out_size, void* d_ws, size_t ws_size,
                              hipStream_t stream)
{
    const float* x   = (const float*)d_in[0];
    const int*   ei  = (const int*)d_in[1];
    const float* p1  = (const float*)d_in[2];
    const float* p2  = (const float*)d_in[3];
    const float* Wl1 = (const float*)d_in[4];
    const float* bl1 = (const float*)d_in[5];
    const float* Wr1 = (const float*)d_in[6];
    const float* Wl2 = (const float*)d_in[7];
    const float* bl2 = (const float*)d_in[8];
    const float* Wr2 = (const float*)d_in[9];
    const int* src = ei;
    const int* dst = ei + N_EDGES;

    char* wp = (char*)d_ws;
    __bf16* xb   = (__bf16*)wp; wp += (size_t)N_NODES * 128 * 2;
    __bf16* aggb = (__bf16*)wp; wp += (size_t)N_NODES * 128 * 2;
    __bf16* t2b  = (__bf16*)wp; wp += (size_t)N_NODES * 128 * 2;
    __bf16* Wl1p = (__bf16*)wp; wp += 128 * 256 * 2;
    __bf16* Wr1p = (__bf16*)wp; wp += 128 * 256 * 2;
    __bf16* Wl2p = (__bf16*)wp; wp += 256 * 128 * 2;
    __bf16* Wr2p = (__bf16*)wp; wp += 256 * 128 * 2;
    int* deg     = (int*)wp; wp += (size_t)N_NODES * 4;
    int* cursor  = (int*)wp; wp += (size_t)N_NODES * 4;
    int* rowp    = (int*)wp; wp += (size_t)(N_NODES + 1) * 4 + 12;
    int* es      = (int*)wp;

    hipMemsetAsync(deg,    0, (size_t)N_NODES * 4, stream);
    hipMemsetAsync(cursor, 0, (size_t)N_NODES * 4, stream);

    const int eblocks = (N_EDGES + 255) / 256;
    const int gblocks = (N_NODES * 64 + 255) / 256;
    const int n4 = N_NODES * 128 / 4;

    k_cvt_x<<<(n4 + 255) / 256, 256, 0, stream>>>(x, xb, n4);
    k_pack_w<<<16, 256, 0, stream>>>(Wl1, Wl1p, 128, 256);
    k_pack_w<<<16, 256, 0, stream>>>(Wr1, Wr1p, 128, 256);
    k_pack_w<<<16, 256, 0, stream>>>(Wl2, Wl2p, 256, 128);
    k_pack_w<<<16, 256, 0, stream>>>(Wr2, Wr2p, 256, 128);
    k_deg<<<eblocks, 256, 0, stream>>>(dst, deg);
    k_scan<<<1, 1024, 0, stream>>>(deg, rowp);
    k_fill<<<eblocks, 256, 0, stream>>>(src, dst, rowp, cursor, es);

    k_gather16<0><<<gblocks, 256, 0, stream>>>(rowp, es, xb, aggb);
    k_fused<<<(N_NODES + 63) / 64, 256, 0, stream>>>(
        aggb, xb, Wl1p, Wr1p, bl1, p1, Wl2p, Wr2p, bl2, p2, t2b, (float*)d_out);
    k_gather16<1><<<gblocks, 256, 0, stream>>>(rowp, es, t2b, (void*)d_out);
}

// Round 6
// 609.359 us; speedup vs baseline: 1.8040x; 1.1066x over previous
//
#include <hip/hip_runtime.h>

#define N_NODES 100000
#define N_EDGES 1600000
// D_IN=128, D_HID=256, D_OUT=128

typedef float v4f __attribute__((ext_vector_type(4)));
typedef __bf16 v8bf __attribute__((ext_vector_type(8)));
typedef __bf16 v4bf __attribute__((ext_vector_type(4)));
typedef unsigned int v4u __attribute__((ext_vector_type(4)));

union FragU { v4u u; v8bf b; };
union PkU { unsigned int u; __bf16 h[2]; };
union Pk2 { uint2 u2; __bf16 h[4]; };

__device__ __forceinline__ int clampN(int v) {
    return v < 0 ? 0 : (v >= N_NODES ? N_NODES - 1 : v);
}
__device__ __forceinline__ float bfhi(unsigned int u) { return __uint_as_float(u & 0xffff0000u); }
__device__ __forceinline__ float bflo(unsigned int u) { return __uint_as_float(u << 16); }

// ---------------- CSR build ----------------
__global__ __launch_bounds__(256) void k_deg(
    const int* __restrict__ dst, int* __restrict__ deg)
{
    int e = blockIdx.x * 256 + threadIdx.x;
    if (e >= N_EDGES) return;
    atomicAdd(&deg[clampN(dst[e])], 1);
}

__global__ __launch_bounds__(1024) void k_scan(
    const int* __restrict__ deg, int* __restrict__ row_ptr)
{
    __shared__ int ps[1024];
    const int t = threadIdx.x;
    const int chunk = (N_NODES + 1023) / 1024;
    int lo = t * chunk;
    int hi = lo + chunk; if (hi > N_NODES) hi = N_NODES;
    int sum = 0;
    for (int i = lo; i < hi; ++i) sum += deg[i];
    ps[t] = sum;
    __syncthreads();
    for (int off = 1; off < 1024; off <<= 1) {
        int v = ps[t];
        int add = (t >= off) ? ps[t - off] : 0;
        __syncthreads();
        ps[t] = v + add;
        __syncthreads();
    }
    int run = (t > 0) ? ps[t - 1] : 0;
    for (int i = lo; i < hi; ++i) { row_ptr[i] = run; run += deg[i]; }
    if (t == 1023) row_ptr[N_NODES] = ps[1023];
}

__global__ __launch_bounds__(256) void k_fill(
    const int* __restrict__ src, const int* __restrict__ dst,
    const int* __restrict__ row_ptr, int* __restrict__ cursor,
    int* __restrict__ edge_src)
{
    int e = blockIdx.x * 256 + threadIdx.x;
    if (e >= N_EDGES) return;
    int s = clampN(src[e]);
    int d = clampN(dst[e]);
    int pos = atomicAdd(&cursor[d], 1);
    edge_src[row_ptr[d] + pos] = s;
}

// ---------------- dtype prep ----------------
__global__ __launch_bounds__(256) void k_cvt_x(
    const float* __restrict__ x, __bf16* __restrict__ xb, int n4)
{
    int t = blockIdx.x * 256 + threadIdx.x;
    if (t >= n4) return;
    float4 v = ((const float4*)x)[t];
    v4bf o = { (__bf16)v.x, (__bf16)v.y, (__bf16)v.z, (__bf16)v.w };
    *(v4bf*)(xb + (size_t)t * 4) = o;
}

// pack W [K][N] fp32 -> MFMA b-frag order: frag fi=(kc*NT+nt), lane l, elem j:
//   Wp[(fi*64+l)*8+j] = bf16(W[kc*32+(l>>4)*8+j][nt*16+(l&15)])
__global__ __launch_bounds__(256) void k_pack_w(
    const float* __restrict__ W, __bf16* __restrict__ Wp, int K, int N)
{
    int t = blockIdx.x * 256 + threadIdx.x;
    int NT = N >> 4;
    int total = (K >> 5) * NT * 64;
    if (t >= total) return;
    int l = t & 63;
    int fi = t >> 6;
    int kc = fi / NT, nt = fi % NT;
    int k0 = kc * 32 + (l >> 4) * 8;
    int col = nt * 16 + (l & 15);
    v8bf o;
    #pragma unroll
    for (int j = 0; j < 8; ++j) o[j] = (__bf16)W[(size_t)(k0 + j) * N + col];
    *(v8bf*)(Wp + (size_t)t * 8) = o;
}

// ---------------- CSR mean-gather: one wave per node, pipelined ----------------
// 16 lanes x 16B per edge row; slot = lane>>4 walks edges with stride 4.
// 2-deep row pipeline + index prefetched 2 ahead -> 8 rows in flight per wave.
// MODE 0: write bf16 mean row.  MODE 1: add fp32 mean row into outp.
template<int MODE>
__global__ __launch_bounds__(256) void k_gather16(
    const int* __restrict__ rp, const int* __restrict__ es,
    const __bf16* __restrict__ tab, void* __restrict__ outp)
{
    int wid = (blockIdx.x * 256 + threadIdx.x) >> 6;
    int l = threadIdx.x & 63;
    if (wid >= N_NODES) return;
    int start = rp[wid], end = rp[wid + 1];
    const int slot = l >> 4, c = l & 15;
    float s0 = 0.f, s1 = 0.f, s2 = 0.f, s3 = 0.f;
    float s4 = 0.f, s5 = 0.f, s6 = 0.f, s7 = 0.f;

    int e0 = start + slot;
    bool h0 = e0 < end;
    v4u r0 = {0, 0, 0, 0};
    if (h0) {
        int i0 = es[e0];
        r0 = *(const v4u*)(tab + (size_t)i0 * 128 + c * 8);
    }
    int e1 = e0 + 4;
    bool h1 = e1 < end;
    int i1 = h1 ? es[e1] : 0;

    while (h0) {
        v4u r1 = {0, 0, 0, 0};
        if (h1) r1 = *(const v4u*)(tab + (size_t)i1 * 128 + c * 8);
        int e2 = e1 + 4;
        bool h2 = e2 < end;
        int i2 = h2 ? es[e2] : 0;
        s0 += bflo(r0.x); s1 += bfhi(r0.x);
        s2 += bflo(r0.y); s3 += bfhi(r0.y);
        s4 += bflo(r0.z); s5 += bfhi(r0.z);
        s6 += bflo(r0.w); s7 += bfhi(r0.w);
        r0 = r1; h0 = h1; h1 = h2; i1 = i2; e1 = e2;
    }

    s0 += __shfl_xor(s0, 16); s1 += __shfl_xor(s1, 16);
    s2 += __shfl_xor(s2, 16); s3 += __shfl_xor(s3, 16);
    s4 += __shfl_xor(s4, 16); s5 += __shfl_xor(s5, 16);
    s6 += __shfl_xor(s6, 16); s7 += __shfl_xor(s7, 16);
    s0 += __shfl_xor(s0, 32); s1 += __shfl_xor(s1, 32);
    s2 += __shfl_xor(s2, 32); s3 += __shfl_xor(s3, 32);
    s4 += __shfl_xor(s4, 32); s5 += __shfl_xor(s5, 32);
    s6 += __shfl_xor(s6, 32); s7 += __shfl_xor(s7, 32);
    float invd = 1.f / fmaxf((float)(end - start), 1.f);
    if (slot == 0) {
        if (MODE == 0) {
            PkU a, b, cc, d;
            a.h[0] = (__bf16)(s0 * invd); a.h[1] = (__bf16)(s1 * invd);
            b.h[0] = (__bf16)(s2 * invd); b.h[1] = (__bf16)(s3 * invd);
            cc.h[0] = (__bf16)(s4 * invd); cc.h[1] = (__bf16)(s5 * invd);
            d.h[0] = (__bf16)(s6 * invd); d.h[1] = (__bf16)(s7 * invd);
            v4u o = { a.u, b.u, cc.u, d.u };
            ((v4u*)outp)[(size_t)wid * 16 + c] = o;
        } else {
            float4* o4 = (float4*)outp + (size_t)wid * 32 + c * 2;
            float4 va = o4[0], vb = o4[1];
            va.x += s0 * invd; va.y += s1 * invd; va.z += s2 * invd; va.w += s3 * invd;
            vb.x += s4 * invd; vb.y += s5 * invd; vb.z += s6 * invd; vb.w += s7 * invd;
            o4[0] = va; o4[1] = vb;
        }
    }
}

// ---------------- fused MFMA, register-lean ----------------
// 256 thr = 4 waves; wave w owns rows [w*16, w*16+16) of the 64-row tile.
// G1 in four 64-col quarters (acc=16 regs) -> raw acc to swizzled LDS;
// coalesced pass adds p1+bl1 into LDS; G2 in two 64-col halves.
__global__ __launch_bounds__(256, 3) void k_fused(
    const __bf16* __restrict__ aggb, const __bf16* __restrict__ xb,
    const __bf16* __restrict__ Wl1p, const __bf16* __restrict__ Wr1p,
    const float* __restrict__ bl1, const float* __restrict__ p1,
    const __bf16* __restrict__ Wl2p, const __bf16* __restrict__ Wr2p,
    const float* __restrict__ bl2, const float* __restrict__ p2,
    __bf16* __restrict__ t2b, float* __restrict__ outp)
{
    __shared__ __bf16 hS[64 * 256];
    char* hB = (char*)hS;
    const int tid = threadIdx.x;
    const int l = tid & 63, w = tid >> 6;
    const int brow = blockIdx.x * 64;
    const int lrow = l & 15, kg = l >> 4;
    const v4f zf = {0.f, 0.f, 0.f, 0.f};

    // A-fragments for all of K (32 VGPRs), rows = wave's 16 rows
    int arow = brow + w * 16 + lrow;
    if (arow >= N_NODES) arow = N_NODES - 1;
    FragU ag[4], xv[4];
    #pragma unroll
    for (int kc = 0; kc < 4; ++kc) {
        size_t off = (size_t)arow * 128 + kc * 64 / 2 * 2 + kc * 0;  // row*128 + kc*32
        off = (size_t)arow * 128 + kc * 32 + kg * 8;
        ag[kc].u = *(const v4u*)(aggb + off);
        xv[kc].u = *(const v4u*)(xb + off);
    }

    // ---- G1: four 64-col quarters ----
    #pragma unroll
    for (int ch = 0; ch < 4; ++ch) {
        v4f acc[4];
        #pragma unroll
        for (int nt = 0; nt < 4; ++nt) acc[nt] = zf;
        #pragma unroll
        for (int kc = 0; kc < 4; ++kc) {
            FragU bwl[4], bwr[4];
            #pragma unroll
            for (int nt = 0; nt < 4; ++nt) {
                int fi = kc * 16 + ch * 4 + nt;
                bwl[nt].u = *(const v4u*)(Wl1p + ((size_t)fi * 64 + l) * 8);
                bwr[nt].u = *(const v4u*)(Wr1p + ((size_t)fi * 64 + l) * 8);
            }
            #pragma unroll
            for (int nt = 0; nt < 4; ++nt) {
                acc[nt] = __builtin_amdgcn_mfma_f32_16x16x32_bf16(ag[kc].b, bwl[nt].b, acc[nt], 0, 0, 0);
                acc[nt] = __builtin_amdgcn_mfma_f32_16x16x32_bf16(xv[kc].b, bwr[nt].b, acc[nt], 0, 0, 0);
            }
        }
        // raw acc -> swizzled LDS (D layout: row=(l>>4)*4+r, col=nt*16+(l&15))
        #pragma unroll
        for (int nt = 0; nt < 4; ++nt)
            #pragma unroll
            for (int r = 0; r < 4; ++r) {
                int row = w * 16 + kg * 4 + r;
                int col = ch * 64 + nt * 16 + lrow;
                int byte = (row * 512 + col * 2) ^ ((row & 7) << 4);
                *(__bf16*)(hB + byte) = (__bf16)acc[nt][r];
            }
    }
    __syncthreads();

    // ---- coalesced p1 + bl1 add into LDS ----
    #pragma unroll
    for (int it = 0; it < 16; ++it) {
        int chunk = it * 256 + tid;      // 4096 chunks = 64 rows x 64 float4
        int row = chunk >> 6, c4 = chunk & 63;
        int grow = brow + row;
        if (grow < N_NODES) {
            float4 pv = ((const float4*)p1)[(size_t)grow * 64 + c4];
            float4 bv = ((const float4*)bl1)[c4];
            int byte = (row * 512 + c4 * 8) ^ ((row & 7) << 4);
            uint2* lp = (uint2*)(hB + byte);
            Pk2 pk; pk.u2 = *lp;
            pk.h[0] = (__bf16)((float)pk.h[0] + pv.x + bv.x);
            pk.h[1] = (__bf16)((float)pk.h[1] + pv.y + bv.y);
            pk.h[2] = (__bf16)((float)pk.h[2] + pv.z + bv.z);
            pk.h[3] = (__bf16)((float)pk.h[3] + pv.w + bv.w);
            *lp = pk.u2;
        }
    }
    __syncthreads();

    // ---- G2: two 64-col halves ----
    #pragma unroll
    for (int chg = 0; chg < 2; ++chg) {
        v4f acct[4], acco[4];
        #pragma unroll
        for (int nt = 0; nt < 4; ++nt) { acct[nt] = zf; acco[nt] = zf; }
        #pragma unroll
        for (int kc = 0; kc < 8; ++kc) {
            FragU a;
            {
                int row = w * 16 + lrow;
                int byte = (row * 512 + kc * 64 + kg * 16) ^ ((row & 7) << 4);
                a.u = *(const v4u*)(hB + byte);
            }
            FragU bwl[4], bwr[4];
            #pragma unroll
            for (int nt = 0; nt < 4; ++nt) {
                int fi = kc * 8 + chg * 4 + nt;
                bwl[nt].u = *(const v4u*)(Wl2p + ((size_t)fi * 64 + l) * 8);
                bwr[nt].u = *(const v4u*)(Wr2p + ((size_t)fi * 64 + l) * 8);
            }
            #pragma unroll
            for (int nt = 0; nt < 4; ++nt) {
                acct[nt] = __builtin_amdgcn_mfma_f32_16x16x32_bf16(a.b, bwl[nt].b, acct[nt], 0, 0, 0);
                acco[nt] = __builtin_amdgcn_mfma_f32_16x16x32_bf16(a.b, bwr[nt].b, acco[nt], 0, 0, 0);
            }
        }
        #pragma unroll
        for (int nt = 0; nt < 4; ++nt) {
            float bv = bl2[chg * 64 + nt * 16 + lrow];
            #pragma unroll
            for (int r = 0; r < 4; ++r) {
                int row = w * 16 + kg * 4 + r;
                int grow = brow + row;
                if (grow >= N_NODES) continue;
                int col = chg * 64 + nt * 16 + lrow;
                t2b[(size_t)grow * 128 + col] = (__bf16)acct[nt][r];
                outp[(size_t)grow * 128 + col] =
                    acco[nt][r] + bv + p2[(size_t)grow * 128 + col];
            }
        }
    }
}

extern "C" void kernel_launch(void* const* d_in, const int* in_sizes, int n_in,
                              void* d_out, int out_size, void* d_ws, size_t ws_size,
                              hipStream_t stream)
{
    const float* x   = (const float*)d_in[0];
    const int*   ei  = (const int*)d_in[1];
    const float* p1  = (const float*)d_in[2];
    const float* p2  = (const float*)d_in[3];
    const float* Wl1 = (const float*)d_in[4];
    const float* bl1 = (const float*)d_in[5];
    const float* Wr1 = (const float*)d_in[6];
    const float* Wl2 = (const float*)d_in[7];
    const float* bl2 = (const float*)d_in[8];
    const float* Wr2 = (const float*)d_in[9];
    const int* src = ei;
    const int* dst = ei + N_EDGES;

    char* wp = (char*)d_ws;
    __bf16* xb   = (__bf16*)wp; wp += (size_t)N_NODES * 128 * 2;
    __bf16* aggb = (__bf16*)wp; wp += (size_t)N_NODES * 128 * 2;
    __bf16* t2b  = (__bf16*)wp; wp += (size_t)N_NODES * 128 * 2;
    __bf16* Wl1p = (__bf16*)wp; wp += 128 * 256 * 2;
    __bf16* Wr1p = (__bf16*)wp; wp += 128 * 256 * 2;
    __bf16* Wl2p = (__bf16*)wp; wp += 256 * 128 * 2;
    __bf16* Wr2p = (__bf16*)wp; wp += 256 * 128 * 2;
    int* deg     = (int*)wp; wp += (size_t)N_NODES * 4;
    int* cursor  = (int*)wp; wp += (size_t)N_NODES * 4;
    int* rowp    = (int*)wp; wp += (size_t)(N_NODES + 1) * 4 + 12;
    int* es      = (int*)wp;

    hipMemsetAsync(deg,    0, (size_t)N_NODES * 4, stream);
    hipMemsetAsync(cursor, 0, (size_t)N_NODES * 4, stream);

    const int eblocks = (N_EDGES + 255) / 256;
    const int gblocks = (N_NODES * 64 + 255) / 256;
    const int n4 = N_NODES * 128 / 4;

    k_cvt_x<<<(n4 + 255) / 256, 256, 0, stream>>>(x, xb, n4);
    k_pack_w<<<16, 256, 0, stream>>>(Wl1, Wl1p, 128, 256);
    k_pack_w<<<16, 256, 0, stream>>>(Wr1, Wr1p, 128, 256);
    k_pack_w<<<16, 256, 0, stream>>>(Wl2, Wl2p, 256, 128);
    k_pack_w<<<16, 256, 0, stream>>>(Wr2, Wr2p, 256, 128);
    k_deg<<<eblocks, 256, 0, stream>>>(dst, deg);
    k_scan<<<1, 1024, 0, stream>>>(deg, rowp);
    k_fill<<<eblocks, 256, 0, stream>>>(src, dst, rowp, cursor, es);

    k_gather16<0><<<gblocks, 256, 0, stream>>>(rowp, es, xb, aggb);
    k_fused<<<(N_NODES + 63) / 64, 256, 0, stream>>>(
        aggb, xb, Wl1p, Wr1p, bl1, p1, Wl2p, Wr2p, bl2, p2, t2b, (float*)d_out);
    k_gather16<1><<<gblocks, 256, 0, stream>>>(rowp, es, t2b, (void*)d_out);
}

// Round 7
// 467.923 us; speedup vs baseline: 2.3493x; 1.3023x over previous
//
#include <hip/hip_runtime.h>

#define N_NODES 100000
#define N_EDGES 1600000
#define NBLK_SCAN ((N_NODES + 255) / 256)   // 391
// D_IN=128, D_HID=256, D_OUT=128

typedef float v4f __attribute__((ext_vector_type(4)));
typedef __bf16 v8bf __attribute__((ext_vector_type(8)));
typedef __bf16 v4bf __attribute__((ext_vector_type(4)));
typedef unsigned int v4u __attribute__((ext_vector_type(4)));

union FragU { v4u u; v8bf b; };
union PkU { unsigned int u; __bf16 h[2]; };

__device__ __forceinline__ int clampN(int v) {
    return v < 0 ? 0 : (v >= N_NODES ? N_NODES - 1 : v);
}
__device__ __forceinline__ float bfhi(unsigned int u) { return __uint_as_float(u & 0xffff0000u); }
__device__ __forceinline__ float bflo(unsigned int u) { return __uint_as_float(u << 16); }

// ---------------- CSR build ----------------
__global__ __launch_bounds__(256) void k_deg(
    const int* __restrict__ dst, int* __restrict__ deg)
{
    int e = blockIdx.x * 256 + threadIdx.x;
    if (e >= N_EDGES) return;
    atomicAdd(&deg[clampN(dst[e])], 1);
}

// hierarchical scan: per-block sums
__global__ __launch_bounds__(256) void k_scan_part(
    const int* __restrict__ deg, int* __restrict__ part)
{
    int i = blockIdx.x * 256 + threadIdx.x;
    int v = (i < N_NODES) ? deg[i] : 0;
    #pragma unroll
    for (int off = 1; off < 64; off <<= 1) v += __shfl_xor(v, off);
    __shared__ int ws_[4];
    if ((threadIdx.x & 63) == 0) ws_[threadIdx.x >> 6] = v;
    __syncthreads();
    if (threadIdx.x == 0) part[blockIdx.x] = ws_[0] + ws_[1] + ws_[2] + ws_[3];
}

// scan the 391 partials in one block -> exclusive offsets (in place)
__global__ __launch_bounds__(512) void k_scan_top(int* __restrict__ part)
{
    int t = threadIdx.x;
    int v = (t < NBLK_SCAN) ? part[t] : 0;
    int orig = v;
    #pragma unroll
    for (int off = 1; off < 64; off <<= 1) {
        int u = __shfl_up(v, off);
        if ((t & 63) >= off) v += u;
    }
    __shared__ int wsum[8];
    if ((t & 63) == 63) wsum[t >> 6] = v;
    __syncthreads();
    if (t < 64) {
        int s = (t < 8) ? wsum[t] : 0;
        #pragma unroll
        for (int off = 1; off < 8; off <<= 1) {
            int u = __shfl_up(s, off);
            if (t >= off) s += u;
        }
        if (t < 8) wsum[t] = s;   // inclusive wave sums
    }
    __syncthreads();
    int woff = (t >= 64) ? wsum[(t >> 6) - 1] : 0;
    if (t < NBLK_SCAN) part[t] = v + woff - orig;
}

// expand: row_ptr[i] = part[b] + exclusive-scan-within-block
__global__ __launch_bounds__(256) void k_scan_exp(
    const int* __restrict__ deg, const int* __restrict__ part,
    int* __restrict__ row_ptr)
{
    int t = threadIdx.x;
    int i = blockIdx.x * 256 + t;
    int v = (i < N_NODES) ? deg[i] : 0;
    int orig = v;
    #pragma unroll
    for (int off = 1; off < 64; off <<= 1) {
        int u = __shfl_up(v, off);
        if ((t & 63) >= off) v += u;
    }
    __shared__ int wsum[4];
    if ((t & 63) == 63) wsum[t >> 6] = v;
    __syncthreads();
    int wo = 0;
    #pragma unroll
    for (int k = 0; k < 4; ++k) if (k < (t >> 6)) wo += wsum[k];
    int excl = v - orig + wo + part[blockIdx.x];
    if (i < N_NODES) row_ptr[i] = excl;
    if (i == N_NODES - 1) row_ptr[N_NODES] = excl + orig;
}

__global__ __launch_bounds__(256) void k_fill(
    const int* __restrict__ src, const int* __restrict__ dst,
    const int* __restrict__ row_ptr, int* __restrict__ cursor,
    int* __restrict__ edge_src)
{
    int e = blockIdx.x * 256 + threadIdx.x;
    if (e >= N_EDGES) return;
    int s = clampN(src[e]);
    int d = clampN(dst[e]);
    int pos = atomicAdd(&cursor[d], 1);
    edge_src[row_ptr[d] + pos] = s;
}

// ---------------- dtype prep ----------------
// x fp32 -> bf16 into the SECOND half of interleaved A' rows [agg(128) | x(128)]
__global__ __launch_bounds__(256) void k_cvt_x(
    const float* __restrict__ x, __bf16* __restrict__ a2, int n4)
{
    int t = blockIdx.x * 256 + threadIdx.x;
    if (t >= n4) return;
    float4 v = ((const float4*)x)[t];
    int row = t >> 5, c4 = t & 31;
    v4bf o = { (__bf16)v.x, (__bf16)v.y, (__bf16)v.z, (__bf16)v.w };
    *(v4bf*)(a2 + (size_t)row * 256 + 128 + c4 * 4) = o;
}

// pack W [K][N] fp32 -> MFMA b-frag order: frag fi=(kc*NT+nt), lane l, elem j:
//   Wp[(fi*64+l)*8+j] = bf16(W[kc*32+(l>>4)*8+j][nt*16+(l&15)])
__global__ __launch_bounds__(256) void k_pack_w(
    const float* __restrict__ W, __bf16* __restrict__ Wp, int K, int N)
{
    int t = blockIdx.x * 256 + threadIdx.x;
    int NT = N >> 4;
    int total = (K >> 5) * NT * 64;
    if (t >= total) return;
    int l = t & 63;
    int fi = t >> 6;
    int kc = fi / NT, nt = fi % NT;
    int k0 = kc * 32 + (l >> 4) * 8;
    int col = nt * 16 + (l & 15);
    v8bf o;
    #pragma unroll
    for (int j = 0; j < 8; ++j) o[j] = (__bf16)W[(size_t)(k0 + j) * N + col];
    *(v8bf*)(Wp + (size_t)t * 8) = o;
}

// ---------------- CSR mean-gather: one wave per node, pipelined ----------------
// MODE 0: read x-half of A' rows (stride 256, +128), write agg into A' first half.
// MODE 1: read t2b rows (stride 128), add fp32 mean into outp.
template<int MODE>
__global__ __launch_bounds__(256) void k_gather16(
    const int* __restrict__ rp, const int* __restrict__ es,
    const __bf16* __restrict__ tab, void* __restrict__ outp)
{
    int wid = (blockIdx.x * 256 + threadIdx.x) >> 6;
    int l = threadIdx.x & 63;
    if (wid >= N_NODES) return;
    int start = rp[wid], end = rp[wid + 1];
    const int slot = l >> 4, c = l & 15;
    float s0 = 0.f, s1 = 0.f, s2 = 0.f, s3 = 0.f;
    float s4 = 0.f, s5 = 0.f, s6 = 0.f, s7 = 0.f;

    int e0 = start + slot;
    bool h0 = e0 < end;
    v4u r0 = {0, 0, 0, 0};
    if (h0) {
        int i0 = es[e0];
        r0 = (MODE == 0)
           ? *(const v4u*)(tab + (size_t)i0 * 256 + 128 + c * 8)
           : *(const v4u*)(tab + (size_t)i0 * 128 + c * 8);
    }
    int e1 = e0 + 4;
    bool h1 = e1 < end;
    int i1 = h1 ? es[e1] : 0;

    while (h0) {
        v4u r1 = {0, 0, 0, 0};
        if (h1) r1 = (MODE == 0)
                   ? *(const v4u*)(tab + (size_t)i1 * 256 + 128 + c * 8)
                   : *(const v4u*)(tab + (size_t)i1 * 128 + c * 8);
        int e2 = e1 + 4;
        bool h2 = e2 < end;
        int i2 = h2 ? es[e2] : 0;
        s0 += bflo(r0.x); s1 += bfhi(r0.x);
        s2 += bflo(r0.y); s3 += bfhi(r0.y);
        s4 += bflo(r0.z); s5 += bfhi(r0.z);
        s6 += bflo(r0.w); s7 += bfhi(r0.w);
        r0 = r1; h0 = h1; h1 = h2; i1 = i2; e1 = e2;
    }

    s0 += __shfl_xor(s0, 16); s1 += __shfl_xor(s1, 16);
    s2 += __shfl_xor(s2, 16); s3 += __shfl_xor(s3, 16);
    s4 += __shfl_xor(s4, 16); s5 += __shfl_xor(s5, 16);
    s6 += __shfl_xor(s6, 16); s7 += __shfl_xor(s7, 16);
    s0 += __shfl_xor(s0, 32); s1 += __shfl_xor(s1, 32);
    s2 += __shfl_xor(s2, 32); s3 += __shfl_xor(s3, 32);
    s4 += __shfl_xor(s4, 32); s5 += __shfl_xor(s5, 32);
    s6 += __shfl_xor(s6, 32); s7 += __shfl_xor(s7, 32);
    float invd = 1.f / fmaxf((float)(end - start), 1.f);
    if (slot == 0) {
        if (MODE == 0) {
            PkU a, b, cc, d;
            a.h[0] = (__bf16)(s0 * invd); a.h[1] = (__bf16)(s1 * invd);
            b.h[0] = (__bf16)(s2 * invd); b.h[1] = (__bf16)(s3 * invd);
            cc.h[0] = (__bf16)(s4 * invd); cc.h[1] = (__bf16)(s5 * invd);
            d.h[0] = (__bf16)(s6 * invd); d.h[1] = (__bf16)(s7 * invd);
            v4u o = { a.u, b.u, cc.u, d.u };
            ((v4u*)outp)[(size_t)wid * 32 + c] = o;   // A' first half
        } else {
            float4* o4 = (float4*)outp + (size_t)wid * 32 + c * 2;
            float4 va = o4[0], vb = o4[1];
            va.x += s0 * invd; va.y += s1 * invd; va.z += s2 * invd; va.w += s3 * invd;
            vb.x += s4 * invd; vb.y += s5 * invd; vb.z += s6 * invd; vb.w += s7 * invd;
            o4[0] = va; o4[1] = vb;
        }
    }
}

// ---------------- weight-stationary GEMM ----------------
// A: rows of 256 bf16 (A' or h), padded to tile*64+64 rows.
// 512 thr = 8 waves; wave w owns 32 output cols; its full B panel (8 kc x 2 nt
// frags = 64 VGPRs) loaded once from packed weights. A-tile (64x256) staged into
// XOR-swizzled LDS, then per row-frag: 8 ds_read_b128 + 16 MFMAs.
// LAYER 1: out = A'@[Wl1;Wr1] + bl1 + p1 -> h (bf16, 256 cols)
// LAYER 2: cols 0-127 -> t2b (bf16); cols 128-255 -> outp = .. + bl2 + p2 (f32)
template<int LAYER>
__global__ __launch_bounds__(512, 2) void k_gws(
    const __bf16* __restrict__ A,
    const __bf16* __restrict__ WpA, const __bf16* __restrict__ WpB,
    const float* __restrict__ bias, const float* __restrict__ pert,
    __bf16* __restrict__ outb, float* __restrict__ outf)
{
    __shared__ char aS[32768];
    const int tid = threadIdx.x;
    const int w = tid >> 6, l = tid & 63;
    const int lrow = l & 15, kg = l >> 4;

    // per-wave resident B fragments
    FragU bw[8][2];
    #pragma unroll
    for (int kc = 0; kc < 8; ++kc)
        #pragma unroll
        for (int nt = 0; nt < 2; ++nt) {
            const __bf16* Wp;
            int fi;
            if (LAYER == 1) {               // B' = [Wl1 ; Wr1] (K-concat), NT=16
                Wp = (kc < 4) ? WpA : WpB;
                fi = (kc & 3) * 16 + w * 2 + nt;
            } else {                        // B'' = [Wl2 | Wr2] (N-concat), NT=8
                Wp = (w < 4) ? WpA : WpB;
                fi = kc * 8 + (w & 3) * 2 + nt;
            }
            bw[kc][nt].u = *(const v4u*)(Wp + ((size_t)fi * 64 + l) * 8);
        }

    float bv[2];
    #pragma unroll
    for (int nt = 0; nt < 2; ++nt) {
        if (LAYER == 1) bv[nt] = bias[w * 32 + nt * 16 + lrow];
        else            bv[nt] = (w >= 4) ? bias[(w - 4) * 32 + nt * 16 + lrow] : 0.f;
    }

    const int row0 = blockIdx.x * 64;

    // stage A-tile (reg-staged, swizzled ds_write)
    #pragma unroll
    for (int cchunk = 0; cchunk < 4; ++cchunk) {
        int chunk = cchunk * 512 + tid;          // 2048 chunks = 64 rows x 32 x 16B
        int row = chunk >> 5, col16 = chunk & 31;
        v4u v = *(const v4u*)(A + (size_t)(row0 + row) * 256 + col16 * 8);
        int byte = (row * 512 + col16 * 16) ^ ((row & 7) << 4);
        *(v4u*)(aS + byte) = v;
    }
    __syncthreads();

    const v4f zf = {0.f, 0.f, 0.f, 0.f};
    #pragma unroll
    for (int rf = 0; rf < 4; ++rf) {
        const int arow = rf * 16 + lrow;
        FragU a[8];
        #pragma unroll
        for (int kc = 0; kc < 8; ++kc) {
            int byte = arow * 512 + ((kc * 64 + kg * 16) ^ ((arow & 7) << 4));
            a[kc].u = *(const v4u*)(aS + byte);
        }
        v4f acc[2] = {zf, zf};
        #pragma unroll
        for (int kc = 0; kc < 8; ++kc) {
            acc[0] = __builtin_amdgcn_mfma_f32_16x16x32_bf16(a[kc].b, bw[kc][0].b, acc[0], 0, 0, 0);
            acc[1] = __builtin_amdgcn_mfma_f32_16x16x32_bf16(a[kc].b, bw[kc][1].b, acc[1], 0, 0, 0);
        }
        // epilogue (D layout: row=(l>>4)*4+r, col=l&15)
        #pragma unroll
        for (int nt = 0; nt < 2; ++nt) {
            #pragma unroll
            for (int r = 0; r < 4; ++r) {
                int row = row0 + rf * 16 + kg * 4 + r;
                if (row >= N_NODES) continue;
                if (LAYER == 1) {
                    int col = w * 32 + nt * 16 + lrow;
                    float hv = acc[nt][r] + bv[nt] + pert[(size_t)row * 256 + col];
                    outb[(size_t)row * 256 + col] = (__bf16)hv;
                } else {
                    if (w < 4) {
                        int col = w * 32 + nt * 16 + lrow;
                        outb[(size_t)row * 128 + col] = (__bf16)acc[nt][r];
                    } else {
                        int oc = (w - 4) * 32 + nt * 16 + lrow;
                        outf[(size_t)row * 128 + oc] =
                            acc[nt][r] + bv[nt] + pert[(size_t)row * 128 + oc];
                    }
                }
            }
        }
    }
}

extern "C" void kernel_launch(void* const* d_in, const int* in_sizes, int n_in,
                              void* d_out, int out_size, void* d_ws, size_t ws_size,
                              hipStream_t stream)
{
    const float* x   = (const float*)d_in[0];
    const int*   ei  = (const int*)d_in[1];
    const float* p1  = (const float*)d_in[2];
    const float* p2  = (const float*)d_in[3];
    const float* Wl1 = (const float*)d_in[4];
    const float* bl1 = (const float*)d_in[5];
    const float* Wr1 = (const float*)d_in[6];
    const float* Wl2 = (const float*)d_in[7];
    const float* bl2 = (const float*)d_in[8];
    const float* Wr2 = (const float*)d_in[9];
    const int* src = ei;
    const int* dst = ei + N_EDGES;

    const size_t NPAD = (size_t)N_NODES + 64;
    char* wp = (char*)d_ws;
    __bf16* a2   = (__bf16*)wp; wp += NPAD * 256 * 2;   // A' = [agg | x]
    __bf16* hb   = (__bf16*)wp; wp += NPAD * 256 * 2;   // h
    __bf16* t2b  = (__bf16*)wp; wp += (size_t)N_NODES * 128 * 2;
    __bf16* Wl1p = (__bf16*)wp; wp += 128 * 256 * 2;
    __bf16* Wr1p = (__bf16*)wp; wp += 128 * 256 * 2;
    __bf16* Wl2p = (__bf16*)wp; wp += 256 * 128 * 2;
    __bf16* Wr2p = (__bf16*)wp; wp += 256 * 128 * 2;
    int* deg     = (int*)wp; wp += (size_t)N_NODES * 4;
    int* cursor  = (int*)wp; wp += (size_t)N_NODES * 4;
    int* part    = (int*)wp; wp += 512 * 4;
    int* rowp    = (int*)wp; wp += (size_t)(N_NODES + 1) * 4 + 12;
    int* es      = (int*)wp;

    hipMemsetAsync(deg,    0, (size_t)N_NODES * 4, stream);
    hipMemsetAsync(cursor, 0, (size_t)N_NODES * 4, stream);

    const int eblocks = (N_EDGES + 255) / 256;
    const int gblocks = (N_NODES * 64 + 255) / 256;
    const int n4 = N_NODES * 128 / 4;
    const int tiles = (N_NODES + 63) / 64;

    k_cvt_x<<<(n4 + 255) / 256, 256, 0, stream>>>(x, a2, n4);
    k_pack_w<<<16, 256, 0, stream>>>(Wl1, Wl1p, 128, 256);
    k_pack_w<<<16, 256, 0, stream>>>(Wr1, Wr1p, 128, 256);
    k_pack_w<<<16, 256, 0, stream>>>(Wl2, Wl2p, 256, 128);
    k_pack_w<<<16, 256, 0, stream>>>(Wr2, Wr2p, 256, 128);
    k_deg<<<eblocks, 256, 0, stream>>>(dst, deg);
    k_scan_part<<<NBLK_SCAN, 256, 0, stream>>>(deg, part);
    k_scan_top<<<1, 512, 0, stream>>>(part);
    k_scan_exp<<<NBLK_SCAN, 256, 0, stream>>>(deg, part, rowp);
    k_fill<<<eblocks, 256, 0, stream>>>(src, dst, rowp, cursor, es);

    k_gather16<0><<<gblocks, 256, 0, stream>>>(rowp, es, a2, a2);
    k_gws<1><<<tiles, 512, 0, stream>>>(a2, Wl1p, Wr1p, bl1, p1, hb, nullptr);
    k_gws<2><<<tiles, 512, 0, stream>>>(hb, Wl2p, Wr2p, bl2, p2, t2b, (float*)d_out);
    k_gather16<1><<<gblocks, 256, 0, stream>>>(rowp, es, t2b, (void*)d_out);
}

// Round 8
// 368.521 us; speedup vs baseline: 2.9830x; 1.2697x over previous
//
#include <hip/hip_runtime.h>

#define N_NODES 100000
#define N_EDGES 1600000
#define NBUCK 196                 // ceil(100000 / 512)
#define CAP_BIN 64                // LDS bin depth in k_bin
#define CAP_B 12288               // per-bucket src staging in k_bucket (mean 8163)
// D_IN=128, D_HID=256, D_OUT=128

typedef float v4f __attribute__((ext_vector_type(4)));
typedef __bf16 v8bf __attribute__((ext_vector_type(8)));
typedef __bf16 v4bf __attribute__((ext_vector_type(4)));
typedef unsigned int v4u __attribute__((ext_vector_type(4)));

union FragU { v4u u; v8bf b; };
union PkU { unsigned int u; __bf16 h[2]; };

__device__ __forceinline__ int clampN(int v) {
    return v < 0 ? 0 : (v >= N_NODES ? N_NODES - 1 : v);
}
__device__ __forceinline__ float bfhi(unsigned int u) { return __uint_as_float(u & 0xffff0000u); }
__device__ __forceinline__ float bflo(unsigned int u) { return __uint_as_float(u << 16); }

// ---------------- CSR build: bucketed counting sort ----------------
// Pass 1: per-block LDS histogram of 196 buckets -> global atomic flush
__global__ __launch_bounds__(256) void k_count(
    const int* __restrict__ dst, int* __restrict__ bucketCnt)
{
    __shared__ int h[NBUCK];
    const int tid = threadIdx.x;
    for (int i = tid; i < NBUCK; i += 256) h[i] = 0;
    __syncthreads();
    int e0 = blockIdx.x * 4096;
    int e1 = e0 + 4096; if (e1 > N_EDGES) e1 = N_EDGES;
    for (int e = e0 + tid; e < e1; e += 256)
        atomicAdd(&h[clampN(dst[e]) >> 9], 1);
    __syncthreads();
    for (int i = tid; i < NBUCK; i += 256)
        if (h[i]) atomicAdd(&bucketCnt[i], h[i]);
}

// Pass 2: scan 196 counts (1 block) -> bases, cursors, rowp[N]
__global__ __launch_bounds__(256) void k_scanb(
    const int* __restrict__ bucketCnt, int* __restrict__ baseB,
    int* __restrict__ gcur, int* __restrict__ rowp)
{
    const int t = threadIdx.x;
    int v = (t < NBUCK) ? bucketCnt[t] : 0;
    int incl = v;
    #pragma unroll
    for (int off = 1; off < 64; off <<= 1) {
        int u = __shfl_up(incl, off);
        if ((t & 63) >= off) incl += u;
    }
    __shared__ int wt[4];
    if ((t & 63) == 63) wt[t >> 6] = incl;
    __syncthreads();
    int woff = 0;
    #pragma unroll
    for (int k = 0; k < 4; ++k) if (k < (t >> 6)) woff += wt[k];
    int excl = woff + incl - v;
    if (t < NBUCK) { baseB[t] = excl; gcur[t] = excl; }
    if (t == NBUCK) { baseB[NBUCK] = excl; rowp[N_NODES] = excl; }
}

// Pass 3: LDS-bin edges, burst-flush contiguous runs into bucket regions
__global__ __launch_bounds__(256) void k_bin(
    const int* __restrict__ src, const int* __restrict__ dst,
    int* __restrict__ gcur, unsigned int* __restrict__ packed)
{
    __shared__ unsigned int bins[256 * CAP_BIN];   // 64 KB
    __shared__ int cnt[256];
    const int tid = threadIdx.x;
    cnt[tid] = 0;
    __syncthreads();
    const int epb = (N_EDGES + gridDim.x - 1) / gridDim.x;
    int e0 = blockIdx.x * epb;
    int e1 = e0 + epb; if (e1 > N_EDGES) e1 = N_EDGES;
    for (int ch = e0; ch < e1; ch += 4096) {
        int chEnd = ch + 4096; if (chEnd > e1) chEnd = e1;
        for (int e = ch + tid; e < chEnd; e += 256) {
            int s = clampN(src[e]);
            int d = clampN(dst[e]);
            unsigned int val = (unsigned int)s | ((unsigned int)(d & 511) << 17);
            int b = d >> 9;
            int slot = atomicAdd(&cnt[b], 1);
            if (slot < CAP_BIN) bins[b * CAP_BIN + slot] = val;
            else {                                   // spill (correctness fallback)
                int g = atomicAdd(&gcur[b], 1);
                packed[g] = val;
            }
        }
        __syncthreads();
        int n = cnt[tid]; if (n > CAP_BIN) n = CAP_BIN;
        if (tid < NBUCK && n > 0) {
            int g = atomicAdd(&gcur[tid], n);
            for (int j = 0; j < n; ++j) packed[g + j] = bins[tid * CAP_BIN + j];
        }
        __syncthreads();
        cnt[tid] = 0;
        __syncthreads();
    }
}

// Pass 4: per bucket: local hist+scan -> rowp; arrange srcs in LDS; coalesced out
__global__ __launch_bounds__(256) void k_bucket(
    const int* __restrict__ baseB, const unsigned int* __restrict__ packed,
    int* __restrict__ rowp, int* __restrict__ edge_src)
{
    __shared__ int hist[512], cur[512];
    __shared__ int wt[4];
    __shared__ unsigned int buf[CAP_B];            // 48 KB
    const int b = blockIdx.x, tid = threadIdx.x;
    const int lo = baseB[b], hi = baseB[b + 1], c = hi - lo;
    for (int i = tid; i < 512; i += 256) hist[i] = 0;
    __syncthreads();
    for (int e = tid; e < c; e += 256)
        atomicAdd(&hist[packed[lo + e] >> 17], 1);
    __syncthreads();
    // exclusive scan of 512 (pairs per thread)
    int a0 = hist[2 * tid], a1 = hist[2 * tid + 1];
    int s = a0 + a1;
    int incl = s;
    #pragma unroll
    for (int off = 1; off < 64; off <<= 1) {
        int u = __shfl_up(incl, off);
        if ((tid & 63) >= off) incl += u;
    }
    if ((tid & 63) == 63) wt[tid >> 6] = incl;
    __syncthreads();
    int woff = 0;
    #pragma unroll
    for (int k = 0; k < 4; ++k) if (k < (tid >> 6)) woff += wt[k];
    int ep = woff + incl - s;
    cur[2 * tid] = ep;
    cur[2 * tid + 1] = ep + a0;
    int n0 = b * 512 + 2 * tid;
    if (n0 < N_NODES)     rowp[n0]     = lo + ep;
    if (n0 + 1 < N_NODES) rowp[n0 + 1] = lo + ep + a0;
    __syncthreads();
    for (int e = tid; e < c; e += 256) {
        unsigned int v = packed[lo + e];
        int dl = v >> 17;
        unsigned int sv = v & 0x1FFFFu;
        int pos = atomicAdd(&cur[dl], 1);
        if (pos < CAP_B) buf[pos] = sv;
        else edge_src[lo + pos] = (int)sv;          // spill (never for this input)
    }
    __syncthreads();
    int cc = c < CAP_B ? c : CAP_B;
    for (int e = tid; e < cc; e += 256) edge_src[lo + e] = (int)buf[e];
}

// ---------------- dtype prep ----------------
// x fp32 -> bf16 into the SECOND half of interleaved A' rows [agg(128) | x(128)]
__global__ __launch_bounds__(256) void k_cvt_x(
    const float* __restrict__ x, __bf16* __restrict__ a2, int n4)
{
    int t = blockIdx.x * 256 + threadIdx.x;
    if (t >= n4) return;
    float4 v = ((const float4*)x)[t];
    int row = t >> 5, c4 = t & 31;
    v4bf o = { (__bf16)v.x, (__bf16)v.y, (__bf16)v.z, (__bf16)v.w };
    *(v4bf*)(a2 + (size_t)row * 256 + 128 + c4 * 4) = o;
}

// pack W [K][N] fp32 -> MFMA b-frag order
__global__ __launch_bounds__(256) void k_pack_w(
    const float* __restrict__ W, __bf16* __restrict__ Wp, int K, int N)
{
    int t = blockIdx.x * 256 + threadIdx.x;
    int NT = N >> 4;
    int total = (K >> 5) * NT * 64;
    if (t >= total) return;
    int l = t & 63;
    int fi = t >> 6;
    int kc = fi / NT, nt = fi % NT;
    int k0 = kc * 32 + (l >> 4) * 8;
    int col = nt * 16 + (l & 15);
    v8bf o;
    #pragma unroll
    for (int j = 0; j < 8; ++j) o[j] = (__bf16)W[(size_t)(k0 + j) * N + col];
    *(v8bf*)(Wp + (size_t)t * 8) = o;
}

// ---------------- CSR mean-gather: one wave per node, pipelined ----------------
template<int MODE>
__global__ __launch_bounds__(256) void k_gather16(
    const int* __restrict__ rp, const int* __restrict__ es,
    const __bf16* __restrict__ tab, void* __restrict__ outp)
{
    int wid = (blockIdx.x * 256 + threadIdx.x) >> 6;
    int l = threadIdx.x & 63;
    if (wid >= N_NODES) return;
    int start = rp[wid], end = rp[wid + 1];
    const int slot = l >> 4, c = l & 15;
    float s0 = 0.f, s1 = 0.f, s2 = 0.f, s3 = 0.f;
    float s4 = 0.f, s5 = 0.f, s6 = 0.f, s7 = 0.f;

    int e0 = start + slot;
    bool h0 = e0 < end;
    v4u r0 = {0, 0, 0, 0};
    if (h0) {
        int i0 = es[e0];
        r0 = (MODE == 0)
           ? *(const v4u*)(tab + (size_t)i0 * 256 + 128 + c * 8)
           : *(const v4u*)(tab + (size_t)i0 * 128 + c * 8);
    }
    int e1 = e0 + 4;
    bool h1 = e1 < end;
    int i1 = h1 ? es[e1] : 0;

    while (h0) {
        v4u r1 = {0, 0, 0, 0};
        if (h1) r1 = (MODE == 0)
                   ? *(const v4u*)(tab + (size_t)i1 * 256 + 128 + c * 8)
                   : *(const v4u*)(tab + (size_t)i1 * 128 + c * 8);
        int e2 = e1 + 4;
        bool h2 = e2 < end;
        int i2 = h2 ? es[e2] : 0;
        s0 += bflo(r0.x); s1 += bfhi(r0.x);
        s2 += bflo(r0.y); s3 += bfhi(r0.y);
        s4 += bflo(r0.z); s5 += bfhi(r0.z);
        s6 += bflo(r0.w); s7 += bfhi(r0.w);
        r0 = r1; h0 = h1; h1 = h2; i1 = i2; e1 = e2;
    }

    s0 += __shfl_xor(s0, 16); s1 += __shfl_xor(s1, 16);
    s2 += __shfl_xor(s2, 16); s3 += __shfl_xor(s3, 16);
    s4 += __shfl_xor(s4, 16); s5 += __shfl_xor(s5, 16);
    s6 += __shfl_xor(s6, 16); s7 += __shfl_xor(s7, 16);
    s0 += __shfl_xor(s0, 32); s1 += __shfl_xor(s1, 32);
    s2 += __shfl_xor(s2, 32); s3 += __shfl_xor(s3, 32);
    s4 += __shfl_xor(s4, 32); s5 += __shfl_xor(s5, 32);
    s6 += __shfl_xor(s6, 32); s7 += __shfl_xor(s7, 32);
    float invd = 1.f / fmaxf((float)(end - start), 1.f);
    if (slot == 0) {
        if (MODE == 0) {
            PkU a, b, cc, d;
            a.h[0] = (__bf16)(s0 * invd); a.h[1] = (__bf16)(s1 * invd);
            b.h[0] = (__bf16)(s2 * invd); b.h[1] = (__bf16)(s3 * invd);
            cc.h[0] = (__bf16)(s4 * invd); cc.h[1] = (__bf16)(s5 * invd);
            d.h[0] = (__bf16)(s6 * invd); d.h[1] = (__bf16)(s7 * invd);
            v4u o = { a.u, b.u, cc.u, d.u };
            ((v4u*)outp)[(size_t)wid * 32 + c] = o;   // A' first half
        } else {
            float4* o4 = (float4*)outp + (size_t)wid * 32 + c * 2;
            float4 va = o4[0], vb = o4[1];
            va.x += s0 * invd; va.y += s1 * invd; va.z += s2 * invd; va.w += s3 * invd;
            vb.x += s4 * invd; vb.y += s5 * invd; vb.z += s6 * invd; vb.w += s7 * invd;
            o4[0] = va; o4[1] = vb;
        }
    }
}

// ---------------- weight-stationary GEMM ----------------
template<int LAYER>
__global__ __launch_bounds__(512, 2) void k_gws(
    const __bf16* __restrict__ A,
    const __bf16* __restrict__ WpA, const __bf16* __restrict__ WpB,
    const float* __restrict__ bias, const float* __restrict__ pert,
    __bf16* __restrict__ outb, float* __restrict__ outf)
{
    __shared__ char aS[32768];
    const int tid = threadIdx.x;
    const int w = tid >> 6, l = tid & 63;
    const int lrow = l & 15, kg = l >> 4;

    FragU bw[8][2];
    #pragma unroll
    for (int kc = 0; kc < 8; ++kc)
        #pragma unroll
        for (int nt = 0; nt < 2; ++nt) {
            const __bf16* Wp;
            int fi;
            if (LAYER == 1) {
                Wp = (kc < 4) ? WpA : WpB;
                fi = (kc & 3) * 16 + w * 2 + nt;
            } else {
                Wp = (w < 4) ? WpA : WpB;
                fi = kc * 8 + (w & 3) * 2 + nt;
            }
            bw[kc][nt].u = *(const v4u*)(Wp + ((size_t)fi * 64 + l) * 8);
        }

    float bv[2];
    #pragma unroll
    for (int nt = 0; nt < 2; ++nt) {
        if (LAYER == 1) bv[nt] = bias[w * 32 + nt * 16 + lrow];
        else            bv[nt] = (w >= 4) ? bias[(w - 4) * 32 + nt * 16 + lrow] : 0.f;
    }

    const int row0 = blockIdx.x * 64;

    #pragma unroll
    for (int cchunk = 0; cchunk < 4; ++cchunk) {
        int chunk = cchunk * 512 + tid;
        int row = chunk >> 5, col16 = chunk & 31;
        v4u v = *(const v4u*)(A + (size_t)(row0 + row) * 256 + col16 * 8);
        int byte = (row * 512 + col16 * 16) ^ ((row & 7) << 4);
        *(v4u*)(aS + byte) = v;
    }
    __syncthreads();

    const v4f zf = {0.f, 0.f, 0.f, 0.f};
    #pragma unroll
    for (int rf = 0; rf < 4; ++rf) {
        const int arow = rf * 16 + lrow;
        FragU a[8];
        #pragma unroll
        for (int kc = 0; kc < 8; ++kc) {
            int byte = arow * 512 + ((kc * 64 + kg * 16) ^ ((arow & 7) << 4));
            a[kc].u = *(const v4u*)(aS + byte);
        }
        v4f acc[2] = {zf, zf};
        #pragma unroll
        for (int kc = 0; kc < 8; ++kc) {
            acc[0] = __builtin_amdgcn_mfma_f32_16x16x32_bf16(a[kc].b, bw[kc][0].b, acc[0], 0, 0, 0);
            acc[1] = __builtin_amdgcn_mfma_f32_16x16x32_bf16(a[kc].b, bw[kc][1].b, acc[1], 0, 0, 0);
        }
        #pragma unroll
        for (int nt = 0; nt < 2; ++nt) {
            #pragma unroll
            for (int r = 0; r < 4; ++r) {
                int row = row0 + rf * 16 + kg * 4 + r;
                if (row >= N_NODES) continue;
                if (LAYER == 1) {
                    int col = w * 32 + nt * 16 + lrow;
                    float hv = acc[nt][r] + bv[nt] + pert[(size_t)row * 256 + col];
                    outb[(size_t)row * 256 + col] = (__bf16)hv;
                } else {
                    if (w < 4) {
                        int col = w * 32 + nt * 16 + lrow;
                        outb[(size_t)row * 128 + col] = (__bf16)acc[nt][r];
                    } else {
                        int oc = (w - 4) * 32 + nt * 16 + lrow;
                        outf[(size_t)row * 128 + oc] =
                            acc[nt][r] + bv[nt] + pert[(size_t)row * 128 + oc];
                    }
                }
            }
        }
    }
}

extern "C" void kernel_launch(void* const* d_in, const int* in_sizes, int n_in,
                              void* d_out, int out_size, void* d_ws, size_t ws_size,
                              hipStream_t stream)
{
    const float* x   = (const float*)d_in[0];
    const int*   ei  = (const int*)d_in[1];
    const float* p1  = (const float*)d_in[2];
    const float* p2  = (const float*)d_in[3];
    const float* Wl1 = (const float*)d_in[4];
    const float* bl1 = (const float*)d_in[5];
    const float* Wr1 = (const float*)d_in[6];
    const float* Wl2 = (const float*)d_in[7];
    const float* bl2 = (const float*)d_in[8];
    const float* Wr2 = (const float*)d_in[9];
    const int* src = ei;
    const int* dst = ei + N_EDGES;

    const size_t NPAD = (size_t)N_NODES + 64;
    char* wp = (char*)d_ws;
    __bf16* a2   = (__bf16*)wp; wp += NPAD * 256 * 2;   // A' = [agg | x]
    __bf16* hb   = (__bf16*)wp; wp += NPAD * 256 * 2;   // h
    __bf16* t2b  = (__bf16*)wp; wp += (size_t)N_NODES * 128 * 2;
    __bf16* Wl1p = (__bf16*)wp; wp += 128 * 256 * 2;
    __bf16* Wr1p = (__bf16*)wp; wp += 128 * 256 * 2;
    __bf16* Wl2p = (__bf16*)wp; wp += 256 * 128 * 2;
    __bf16* Wr2p = (__bf16*)wp; wp += 256 * 128 * 2;
    int* bucketCnt = (int*)wp; wp += 512 * 4;
    int* baseB     = (int*)wp; wp += 512 * 4;
    int* gcur      = (int*)wp; wp += 512 * 4;
    int* rowp      = (int*)wp; wp += (size_t)(N_NODES + 1) * 4 + 12;
    unsigned int* packed = (unsigned int*)wp; wp += (size_t)N_EDGES * 4;
    int* es        = (int*)wp;

    hipMemsetAsync(bucketCnt, 0, 512 * 4, stream);

    const int gblocks = (N_NODES * 64 + 255) / 256;
    const int n4 = N_NODES * 128 / 4;
    const int tiles = (N_NODES + 63) / 64;

    k_cvt_x<<<(n4 + 255) / 256, 256, 0, stream>>>(x, a2, n4);
    k_pack_w<<<16, 256, 0, stream>>>(Wl1, Wl1p, 128, 256);
    k_pack_w<<<16, 256, 0, stream>>>(Wr1, Wr1p, 128, 256);
    k_pack_w<<<16, 256, 0, stream>>>(Wl2, Wl2p, 256, 128);
    k_pack_w<<<16, 256, 0, stream>>>(Wr2, Wr2p, 256, 128);

    k_count<<<(N_EDGES + 4095) / 4096, 256, 0, stream>>>(dst, bucketCnt);
    k_scanb<<<1, 256, 0, stream>>>(bucketCnt, baseB, gcur, rowp);
    k_bin<<<256, 256, 0, stream>>>(src, dst, gcur, packed);
    k_bucket<<<NBUCK, 256, 0, stream>>>(baseB, packed, rowp, es);

    k_gather16<0><<<gblocks, 256, 0, stream>>>(rowp, es, a2, a2);
    k_gws<1><<<tiles, 512, 0, stream>>>(a2, Wl1p, Wr1p, bl1, p1, hb, nullptr);
    k_gws<2><<<tiles, 512, 0, stream>>>(hb, Wl2p, Wr2p, bl2, p2, t2b, (float*)d_out);
    k_gather16<1><<<gblocks, 256, 0, stream>>>(rowp, es, t2b, (void*)d_out);
}

// Round 9
// 340.060 us; speedup vs baseline: 3.2327x; 1.0837x over previous
//
#include <hip/hip_runtime.h>

#define N_NODES 100000
#define N_EDGES 1600000
#define NBUCK 196                 // ceil(100000 / 512)
#define CAP_BIN 64                // LDS bin depth in k_bin
#define CAP_B 12288               // per-bucket src staging in k_bucket (mean 8163)
// D_IN=128, D_HID=256, D_OUT=128

typedef float v4f __attribute__((ext_vector_type(4)));
typedef __bf16 v8bf __attribute__((ext_vector_type(8)));
typedef __bf16 v4bf __attribute__((ext_vector_type(4)));
typedef unsigned int v4u __attribute__((ext_vector_type(4)));

union FragU { v4u u; v8bf b; };
union PkU { unsigned int u; __bf16 h[2]; };
union Pk2 { uint2 u2; __bf16 h[4]; };

__device__ __forceinline__ int clampN(int v) {
    return v < 0 ? 0 : (v >= N_NODES ? N_NODES - 1 : v);
}
__device__ __forceinline__ float bfhi(unsigned int u) { return __uint_as_float(u & 0xffff0000u); }
__device__ __forceinline__ float bflo(unsigned int u) { return __uint_as_float(u << 16); }

// ---------------- CSR build: bucketed counting sort ----------------
__global__ __launch_bounds__(256) void k_count(
    const int* __restrict__ dst, int* __restrict__ bucketCnt)
{
    __shared__ int h[NBUCK];
    const int tid = threadIdx.x;
    for (int i = tid; i < NBUCK; i += 256) h[i] = 0;
    __syncthreads();
    int e0 = blockIdx.x * 4096;
    int e1 = e0 + 4096; if (e1 > N_EDGES) e1 = N_EDGES;
    for (int e = e0 + tid; e < e1; e += 256)
        atomicAdd(&h[clampN(dst[e]) >> 9], 1);
    __syncthreads();
    for (int i = tid; i < NBUCK; i += 256)
        if (h[i]) atomicAdd(&bucketCnt[i], h[i]);
}

__global__ __launch_bounds__(256) void k_scanb(
    const int* __restrict__ bucketCnt, int* __restrict__ baseB,
    int* __restrict__ gcur, int* __restrict__ rowp)
{
    const int t = threadIdx.x;
    int v = (t < NBUCK) ? bucketCnt[t] : 0;
    int incl = v;
    #pragma unroll
    for (int off = 1; off < 64; off <<= 1) {
        int u = __shfl_up(incl, off);
        if ((t & 63) >= off) incl += u;
    }
    __shared__ int wt[4];
    if ((t & 63) == 63) wt[t >> 6] = incl;
    __syncthreads();
    int woff = 0;
    #pragma unroll
    for (int k = 0; k < 4; ++k) if (k < (t >> 6)) woff += wt[k];
    int excl = woff + incl - v;
    if (t < NBUCK) { baseB[t] = excl; gcur[t] = excl; }
    if (t == NBUCK) { baseB[NBUCK] = excl; rowp[N_NODES] = excl; }
}

__global__ __launch_bounds__(256) void k_bin(
    const int* __restrict__ src, const int* __restrict__ dst,
    int* __restrict__ gcur, unsigned int* __restrict__ packed)
{
    __shared__ unsigned int bins[256 * CAP_BIN];   // 64 KB
    __shared__ int cnt[256];
    const int tid = threadIdx.x;
    cnt[tid] = 0;
    __syncthreads();
    const int epb = (N_EDGES + gridDim.x - 1) / gridDim.x;
    int e0 = blockIdx.x * epb;
    int e1 = e0 + epb; if (e1 > N_EDGES) e1 = N_EDGES;
    for (int ch = e0; ch < e1; ch += 4096) {
        int chEnd = ch + 4096; if (chEnd > e1) chEnd = e1;
        for (int e = ch + tid; e < chEnd; e += 256) {
            int s = clampN(src[e]);
            int d = clampN(dst[e]);
            unsigned int val = (unsigned int)s | ((unsigned int)(d & 511) << 17);
            int b = d >> 9;
            int slot = atomicAdd(&cnt[b], 1);
            if (slot < CAP_BIN) bins[b * CAP_BIN + slot] = val;
            else {
                int g = atomicAdd(&gcur[b], 1);
                packed[g] = val;
            }
        }
        __syncthreads();
        int n = cnt[tid]; if (n > CAP_BIN) n = CAP_BIN;
        if (tid < NBUCK && n > 0) {
            int g = atomicAdd(&gcur[tid], n);
            for (int j = 0; j < n; ++j) packed[g + j] = bins[tid * CAP_BIN + j];
        }
        __syncthreads();
        cnt[tid] = 0;
        __syncthreads();
    }
}

__global__ __launch_bounds__(256) void k_bucket(
    const int* __restrict__ baseB, const unsigned int* __restrict__ packed,
    int* __restrict__ rowp, int* __restrict__ edge_src)
{
    __shared__ int hist[512], cur[512];
    __shared__ int wt[4];
    __shared__ unsigned int buf[CAP_B];            // 48 KB
    const int b = blockIdx.x, tid = threadIdx.x;
    const int lo = baseB[b], hi = baseB[b + 1], c = hi - lo;
    for (int i = tid; i < 512; i += 256) hist[i] = 0;
    __syncthreads();
    for (int e = tid; e < c; e += 256)
        atomicAdd(&hist[packed[lo + e] >> 17], 1);
    __syncthreads();
    int a0 = hist[2 * tid], a1 = hist[2 * tid + 1];
    int s = a0 + a1;
    int incl = s;
    #pragma unroll
    for (int off = 1; off < 64; off <<= 1) {
        int u = __shfl_up(incl, off);
        if ((tid & 63) >= off) incl += u;
    }
    if ((tid & 63) == 63) wt[tid >> 6] = incl;
    __syncthreads();
    int woff = 0;
    #pragma unroll
    for (int k = 0; k < 4; ++k) if (k < (tid >> 6)) woff += wt[k];
    int ep = woff + incl - s;
    cur[2 * tid] = ep;
    cur[2 * tid + 1] = ep + a0;
    int n0 = b * 512 + 2 * tid;
    if (n0 < N_NODES)     rowp[n0]     = lo + ep;
    if (n0 + 1 < N_NODES) rowp[n0 + 1] = lo + ep + a0;
    __syncthreads();
    for (int e = tid; e < c; e += 256) {
        unsigned int v = packed[lo + e];
        int dl = v >> 17;
        unsigned int sv = v & 0x1FFFFu;
        int pos = atomicAdd(&cur[dl], 1);
        if (pos < CAP_B) buf[pos] = sv;
        else edge_src[lo + pos] = (int)sv;
    }
    __syncthreads();
    int cc = c < CAP_B ? c : CAP_B;
    for (int e = tid; e < cc; e += 256) edge_src[lo + e] = (int)buf[e];
}

// ---------------- dtype prep ----------------
__global__ __launch_bounds__(256) void k_cvt_x(
    const float* __restrict__ x, __bf16* __restrict__ a2, int n4)
{
    int t = blockIdx.x * 256 + threadIdx.x;
    if (t >= n4) return;
    float4 v = ((const float4*)x)[t];
    int row = t >> 5, c4 = t & 31;
    v4bf o = { (__bf16)v.x, (__bf16)v.y, (__bf16)v.z, (__bf16)v.w };
    *(v4bf*)(a2 + (size_t)row * 256 + 128 + c4 * 4) = o;
}

__global__ __launch_bounds__(256) void k_pack_w(
    const float* __restrict__ W, __bf16* __restrict__ Wp, int K, int N)
{
    int t = blockIdx.x * 256 + threadIdx.x;
    int NT = N >> 4;
    int total = (K >> 5) * NT * 64;
    if (t >= total) return;
    int l = t & 63;
    int fi = t >> 6;
    int kc = fi / NT, nt = fi % NT;
    int k0 = kc * 32 + (l >> 4) * 8;
    int col = nt * 16 + (l & 15);
    v8bf o;
    #pragma unroll
    for (int j = 0; j < 8; ++j) o[j] = (__bf16)W[(size_t)(k0 + j) * N + col];
    *(v8bf*)(Wp + (size_t)t * 8) = o;
}

// ---------------- CSR mean-gather ----------------
template<int MODE>
__global__ __launch_bounds__(256) void k_gather16(
    const int* __restrict__ rp, const int* __restrict__ es,
    const __bf16* __restrict__ tab, void* __restrict__ outp)
{
    int wid = (blockIdx.x * 256 + threadIdx.x) >> 6;
    int l = threadIdx.x & 63;
    if (wid >= N_NODES) return;
    int start = rp[wid], end = rp[wid + 1];
    const int slot = l >> 4, c = l & 15;
    float s0 = 0.f, s1 = 0.f, s2 = 0.f, s3 = 0.f;
    float s4 = 0.f, s5 = 0.f, s6 = 0.f, s7 = 0.f;

    int e0 = start + slot;
    bool h0 = e0 < end;
    v4u r0 = {0, 0, 0, 0};
    if (h0) {
        int i0 = es[e0];
        r0 = (MODE == 0)
           ? *(const v4u*)(tab + (size_t)i0 * 256 + 128 + c * 8)
           : *(const v4u*)(tab + (size_t)i0 * 128 + c * 8);
    }
    int e1 = e0 + 4;
    bool h1 = e1 < end;
    int i1 = h1 ? es[e1] : 0;

    while (h0) {
        v4u r1 = {0, 0, 0, 0};
        if (h1) r1 = (MODE == 0)
                   ? *(const v4u*)(tab + (size_t)i1 * 256 + 128 + c * 8)
                   : *(const v4u*)(tab + (size_t)i1 * 128 + c * 8);
        int e2 = e1 + 4;
        bool h2 = e2 < end;
        int i2 = h2 ? es[e2] : 0;
        s0 += bflo(r0.x); s1 += bfhi(r0.x);
        s2 += bflo(r0.y); s3 += bfhi(r0.y);
        s4 += bflo(r0.z); s5 += bfhi(r0.z);
        s6 += bflo(r0.w); s7 += bfhi(r0.w);
        r0 = r1; h0 = h1; h1 = h2; i1 = i2; e1 = e2;
    }

    s0 += __shfl_xor(s0, 16); s1 += __shfl_xor(s1, 16);
    s2 += __shfl_xor(s2, 16); s3 += __shfl_xor(s3, 16);
    s4 += __shfl_xor(s4, 16); s5 += __shfl_xor(s5, 16);
    s6 += __shfl_xor(s6, 16); s7 += __shfl_xor(s7, 16);
    s0 += __shfl_xor(s0, 32); s1 += __shfl_xor(s1, 32);
    s2 += __shfl_xor(s2, 32); s3 += __shfl_xor(s3, 32);
    s4 += __shfl_xor(s4, 32); s5 += __shfl_xor(s5, 32);
    s6 += __shfl_xor(s6, 32); s7 += __shfl_xor(s7, 32);
    float invd = 1.f / fmaxf((float)(end - start), 1.f);
    if (slot == 0) {
        if (MODE == 0) {
            PkU a, b, cc, d;
            a.h[0] = (__bf16)(s0 * invd); a.h[1] = (__bf16)(s1 * invd);
            b.h[0] = (__bf16)(s2 * invd); b.h[1] = (__bf16)(s3 * invd);
            cc.h[0] = (__bf16)(s4 * invd); cc.h[1] = (__bf16)(s5 * invd);
            d.h[0] = (__bf16)(s6 * invd); d.h[1] = (__bf16)(s7 * invd);
            v4u o = { a.u, b.u, cc.u, d.u };
            ((v4u*)outp)[(size_t)wid * 32 + c] = o;   // A' first half
        } else {
            float4* o4 = (float4*)outp + (size_t)wid * 32 + c * 2;
            float4 va = o4[0], vb = o4[1];
            va.x += s0 * invd; va.y += s1 * invd; va.z += s2 * invd; va.w += s3 * invd;
            vb.x += s4 * invd; vb.y += s5 * invd; vb.z += s6 * invd; vb.w += s7 * invd;
            o4[0] = va; o4[1] = vb;
        }
    }
}

// ---------------- weight-stationary GEMM, persistent + pipelined ----------------
__device__ __forceinline__ void ld_stage(
    const __bf16* __restrict__ A, int tile, int tid, v4u st[4])
{
    const int row0 = tile * 64;
    #pragma unroll
    for (int cc = 0; cc < 4; ++cc) {
        int chunk = cc * 512 + tid;              // 2048 = 64 rows x 32 x 16B
        int row = chunk >> 5, col16 = chunk & 31;
        st[cc] = *(const v4u*)(A + (size_t)(row0 + row) * 256 + col16 * 8);
    }
}

// 512 thr = 8 waves; wave w owns 32 output cols (B panel resident, 64 regs).
// Grid-stride persistent; tile t+1's global loads are in flight during all of
// tile t's compute+epilogue (T14). Epilogue goes acc->bf16->hS (swizzled) then
// a fully-coalesced vectorized pass (float4 pert loads, 8/16B stores).
// LAYER 1: outb = h (bf16, 256 cols) = A'@[Wl1;Wr1] + bl1 + p1
// LAYER 2: cols 0-127 -> t2b (bf16 raw); cols 128-255 -> outf = ..+bl2+p2 (f32)
template<int LAYER>
__global__ __launch_bounds__(512, 2) void k_gws(
    const __bf16* __restrict__ A,
    const __bf16* __restrict__ WpA, const __bf16* __restrict__ WpB,
    const float* __restrict__ bias, const float* __restrict__ pert,
    __bf16* __restrict__ outb, float* __restrict__ outf, int ntiles)
{
    __shared__ char aS[32768];
    __shared__ char hS[32768];
    const int tid = threadIdx.x;
    const int w = tid >> 6, l = tid & 63;
    const int lrow = l & 15, kg = l >> 4;
    const v4f zf = {0.f, 0.f, 0.f, 0.f};

    // resident B panel (per-wave columns)
    FragU bw[8][2];
    #pragma unroll
    for (int kc = 0; kc < 8; ++kc)
        #pragma unroll
        for (int nt = 0; nt < 2; ++nt) {
            const __bf16* Wp;
            int fi;
            if (LAYER == 1) {                // B' = [Wl1 ; Wr1] K-concat, NT=16
                Wp = (kc < 4) ? WpA : WpB;
                fi = (kc & 3) * 16 + w * 2 + nt;
            } else {                         // B'' = [Wl2 | Wr2] N-concat, NT=8
                Wp = (w < 4) ? WpA : WpB;
                fi = kc * 8 + (w & 3) * 2 + nt;
            }
            bw[kc][nt].u = *(const v4u*)(Wp + ((size_t)fi * 64 + l) * 8);
        }

    int tile = blockIdx.x;
    v4u st[4];
    if (tile < ntiles) ld_stage(A, tile, tid, st);

    for (; tile < ntiles; tile += gridDim.x) {
        // stage regs -> swizzled LDS (safe: all aS reads ended before prev B_h)
        #pragma unroll
        for (int cc = 0; cc < 4; ++cc) {
            int chunk = cc * 512 + tid;
            int row = chunk >> 5, col16 = chunk & 31;
            int byte = (row * 512 + col16 * 16) ^ ((row & 7) << 4);
            *(v4u*)(aS + byte) = st[cc];
        }
        int nxt = tile + (int)gridDim.x;
        if (nxt < ntiles) ld_stage(A, nxt, tid, st);   // in flight across compute
        __syncthreads();                               // B_a

        const int row0 = tile * 64;
        #pragma unroll
        for (int rf = 0; rf < 4; ++rf) {
            const int arow = rf * 16 + lrow;
            FragU a[8];
            #pragma unroll
            for (int kc = 0; kc < 8; ++kc) {
                int byte = arow * 512 + ((kc * 64 + kg * 16) ^ ((arow & 7) << 4));
                a[kc].u = *(const v4u*)(aS + byte);
            }
            v4f acc[2] = {zf, zf};
            #pragma unroll
            for (int kc = 0; kc < 8; ++kc) {
                acc[0] = __builtin_amdgcn_mfma_f32_16x16x32_bf16(a[kc].b, bw[kc][0].b, acc[0], 0, 0, 0);
                acc[1] = __builtin_amdgcn_mfma_f32_16x16x32_bf16(a[kc].b, bw[kc][1].b, acc[1], 0, 0, 0);
            }
            // raw acc -> bf16 -> swizzled hS (D layout row=(l>>4)*4+r, col=l&15)
            #pragma unroll
            for (int nt = 0; nt < 2; ++nt)
                #pragma unroll
                for (int r = 0; r < 4; ++r) {
                    int row = rf * 16 + kg * 4 + r;
                    int col = w * 32 + nt * 16 + lrow;
                    int byte = (row * 512 + col * 2) ^ ((row & 7) << 4);
                    *(__bf16*)(hS + byte) = (__bf16)acc[nt][r];
                }
        }
        __syncthreads();                               // B_h

        // coalesced epilogue: each wave-iter covers one full 512B row
        #pragma unroll
        for (int it = 0; it < 8; ++it) {
            int chunk = it * 512 + tid;                // 4096 = 64 rows x 64 x 8B
            int row = chunk >> 6, c4 = chunk & 63;
            int grow = row0 + row;
            if (grow >= N_NODES) continue;
            int byte = (row * 512 + c4 * 8) ^ ((row & 7) << 4);
            Pk2 pk; pk.u2 = *(const uint2*)(hS + byte);
            if (LAYER == 1) {
                float4 pv = ((const float4*)pert)[(size_t)grow * 64 + c4];
                float4 bv = ((const float4*)bias)[c4];
                PkU o0, o1;
                o0.h[0] = (__bf16)((float)pk.h[0] + pv.x + bv.x);
                o0.h[1] = (__bf16)((float)pk.h[1] + pv.y + bv.y);
                o1.h[0] = (__bf16)((float)pk.h[2] + pv.z + bv.z);
                o1.h[1] = (__bf16)((float)pk.h[3] + pv.w + bv.w);
                uint2 ov = { o0.u, o1.u };
                *(uint2*)(outb + (size_t)grow * 256 + c4 * 4) = ov;
            } else {
                if (c4 < 32) {                          // t2 half: raw bf16
                    *(uint2*)(outb + (size_t)grow * 128 + c4 * 4) = pk.u2;
                } else {                                // out half: f32 + bias + pert
                    int oc4 = c4 - 32;
                    float4 pv = ((const float4*)pert)[(size_t)grow * 32 + oc4];
                    float4 bv = ((const float4*)bias)[oc4];
                    float4 ov;
                    ov.x = (float)pk.h[0] + pv.x + bv.x;
                    ov.y = (float)pk.h[1] + pv.y + bv.y;
                    ov.z = (float)pk.h[2] + pv.z + bv.z;
                    ov.w = (float)pk.h[3] + pv.w + bv.w;
                    ((float4*)outf)[(size_t)grow * 32 + oc4] = ov;
                }
            }
        }
        // no trailing barrier needed: next aS write is safe after B_h,
        // next hS write is after next B_a (all waves past this epilogue).
    }
}

extern "C" void kernel_launch(void* const* d_in, const int* in_sizes, int n_in,
                              void* d_out, int out_size, void* d_ws, size_t ws_size,
                              hipStream_t stream)
{
    const float* x   = (const float*)d_in[0];
    const int*   ei  = (const int*)d_in[1];
    const float* p1  = (const float*)d_in[2];
    const float* p2  = (const float*)d_in[3];
    const float* Wl1 = (const float*)d_in[4];
    const float* bl1 = (const float*)d_in[5];
    const float* Wr1 = (const float*)d_in[6];
    const float* Wl2 = (const float*)d_in[7];
    const float* bl2 = (const float*)d_in[8];
    const float* Wr2 = (const float*)d_in[9];
    const int* src = ei;
    const int* dst = ei + N_EDGES;

    const size_t NPAD = (size_t)N_NODES + 64;
    char* wp = (char*)d_ws;
    __bf16* a2   = (__bf16*)wp; wp += NPAD * 256 * 2;   // A' = [agg | x]
    __bf16* hb   = (__bf16*)wp; wp += NPAD * 256 * 2;   // h
    __bf16* t2b  = (__bf16*)wp; wp += (size_t)N_NODES * 128 * 2;
    __bf16* Wl1p = (__bf16*)wp; wp += 128 * 256 * 2;
    __bf16* Wr1p = (__bf16*)wp; wp += 128 * 256 * 2;
    __bf16* Wl2p = (__bf16*)wp; wp += 256 * 128 * 2;
    __bf16* Wr2p = (__bf16*)wp; wp += 256 * 128 * 2;
    int* bucketCnt = (int*)wp; wp += 512 * 4;
    int* baseB     = (int*)wp; wp += 512 * 4;
    int* gcur      = (int*)wp; wp += 512 * 4;
    int* rowp      = (int*)wp; wp += (size_t)(N_NODES + 1) * 4 + 12;
    unsigned int* packed = (unsigned int*)wp; wp += (size_t)N_EDGES * 4;
    int* es        = (int*)wp;

    hipMemsetAsync(bucketCnt, 0, 512 * 4, stream);

    const int gblocks = (N_NODES * 64 + 255) / 256;
    const int n4 = N_NODES * 128 / 4;
    const int tiles = (N_NODES + 63) / 64;

    k_cvt_x<<<(n4 + 255) / 256, 256, 0, stream>>>(x, a2, n4);
    k_pack_w<<<16, 256, 0, stream>>>(Wl1, Wl1p, 128, 256);
    k_pack_w<<<16, 256, 0, stream>>>(Wr1, Wr1p, 128, 256);
    k_pack_w<<<16, 256, 0, stream>>>(Wl2, Wl2p, 256, 128);
    k_pack_w<<<16, 256, 0, stream>>>(Wr2, Wr2p, 256, 128);

    k_count<<<(N_EDGES + 4095) / 4096, 256, 0, stream>>>(dst, bucketCnt);
    k_scanb<<<1, 256, 0, stream>>>(bucketCnt, baseB, gcur, rowp);
    k_bin<<<256, 256, 0, stream>>>(src, dst, gcur, packed);
    k_bucket<<<NBUCK, 256, 0, stream>>>(baseB, packed, rowp, es);

    k_gather16<0><<<gblocks, 256, 0, stream>>>(rowp, es, a2, a2);
    k_gws<1><<<512, 512, 0, stream>>>(a2, Wl1p, Wr1p, bl1, p1, hb, nullptr, tiles);
    k_gws<2><<<512, 512, 0, stream>>>(hb, Wl2p, Wr2p, bl2, p2, t2b, (float*)d_out, tiles);
    k_gather16<1><<<gblocks, 256, 0, stream>>>(rowp, es, t2b, (void*)d_out);
}

// Round 10
// 317.372 us; speedup vs baseline: 3.4638x; 1.0715x over previous
//
#include <hip/hip_runtime.h>

#define N_NODES 100000
#define N_EDGES 1600000
#define NBUCK 196                 // ceil(100000 / 512)
#define CAP_BIN 64                // LDS bin depth in k_bin
#define CAP_B 12288               // per-bucket src staging in k_bucket (mean 8163)
#define CVT_BLKS 12500            // N*128/4 / 256
// D_IN=128, D_HID=256, D_OUT=128

typedef float v4f __attribute__((ext_vector_type(4)));
typedef __bf16 v8bf __attribute__((ext_vector_type(8)));
typedef __bf16 v4bf __attribute__((ext_vector_type(4)));
typedef unsigned int v4u __attribute__((ext_vector_type(4)));

union FragU { v4u u; v8bf b; };
union PkU { unsigned int u; __bf16 h[2]; };
union Pk2 { uint2 u2; __bf16 h[4]; };

__device__ __forceinline__ int clampN(int v) {
    return v < 0 ? 0 : (v >= N_NODES ? N_NODES - 1 : v);
}
__device__ __forceinline__ float bfhi(unsigned int u) { return __uint_as_float(u & 0xffff0000u); }
__device__ __forceinline__ float bflo(unsigned int u) { return __uint_as_float(u << 16); }

// ---------------- fused prep: cvt_x | 4x pack_w | bucket count ----------------
__global__ __launch_bounds__(256) void k_prep(
    const float* __restrict__ x, __bf16* __restrict__ a2,
    const float* __restrict__ Wl1, const float* __restrict__ Wr1,
    const float* __restrict__ Wl2, const float* __restrict__ Wr2,
    __bf16* __restrict__ Wl1p, __bf16* __restrict__ Wr1p,
    __bf16* __restrict__ Wl2p, __bf16* __restrict__ Wr2p,
    const int* __restrict__ dst, int* __restrict__ bucketCnt)
{
    const int b = blockIdx.x, tid = threadIdx.x;
    if (b < CVT_BLKS) {
        // x fp32 -> bf16 into SECOND half of A' rows [agg(128) | x(128)]
        int t = b * 256 + tid;                     // t < 3.2M exactly
        float4 v = ((const float4*)x)[t];
        int row = t >> 5, c4 = t & 31;
        v4bf o = { (__bf16)v.x, (__bf16)v.y, (__bf16)v.z, (__bf16)v.w };
        *(v4bf*)(a2 + (size_t)row * 256 + 128 + c4 * 4) = o;
    } else if (b < CVT_BLKS + 64) {
        // pack W [K][N] fp32 -> MFMA b-frag order
        int pb = b - CVT_BLKS;
        int which = pb >> 4;
        int t = (pb & 15) * 256 + tid;             // t < 4096 exactly
        const float* W = which == 0 ? Wl1 : which == 1 ? Wr1 : which == 2 ? Wl2 : Wr2;
        __bf16* Wp     = which == 0 ? Wl1p : which == 1 ? Wr1p : which == 2 ? Wl2p : Wr2p;
        const int N = (which < 2) ? 256 : 128;
        const int NT = N >> 4;
        int l = t & 63;
        int fi = t >> 6;
        int kc = fi / NT, nt = fi % NT;
        int k0 = kc * 32 + (l >> 4) * 8;
        int col = nt * 16 + (l & 15);
        v8bf o;
        #pragma unroll
        for (int j = 0; j < 8; ++j) o[j] = (__bf16)W[(size_t)(k0 + j) * N + col];
        *(v8bf*)(Wp + (size_t)t * 8) = o;
    } else {
        // bucket histogram (LDS) -> global atomic flush
        __shared__ int h[NBUCK];
        for (int i = tid; i < NBUCK; i += 256) h[i] = 0;
        __syncthreads();
        int cb = b - CVT_BLKS - 64;
        int e0 = cb * 4096;
        int e1 = e0 + 4096; if (e1 > N_EDGES) e1 = N_EDGES;
        for (int e = e0 + tid; e < e1; e += 256)
            atomicAdd(&h[clampN(dst[e]) >> 9], 1);
        __syncthreads();
        for (int i = tid; i < NBUCK; i += 256)
            if (h[i]) atomicAdd(&bucketCnt[i], h[i]);
    }
}

// ---------------- CSR build: bucketed counting sort ----------------
__global__ __launch_bounds__(256) void k_scanb(
    const int* __restrict__ bucketCnt, int* __restrict__ baseB,
    int* __restrict__ gcur, int* __restrict__ rowp)
{
    const int t = threadIdx.x;
    int v = (t < NBUCK) ? bucketCnt[t] : 0;
    int incl = v;
    #pragma unroll
    for (int off = 1; off < 64; off <<= 1) {
        int u = __shfl_up(incl, off);
        if ((t & 63) >= off) incl += u;
    }
    __shared__ int wt[4];
    if ((t & 63) == 63) wt[t >> 6] = incl;
    __syncthreads();
    int woff = 0;
    #pragma unroll
    for (int k = 0; k < 4; ++k) if (k < (t >> 6)) woff += wt[k];
    int excl = woff + incl - v;
    if (t < NBUCK) { baseB[t] = excl; gcur[t] = excl; }
    if (t == NBUCK) { baseB[NBUCK] = excl; rowp[N_NODES] = excl; }
}

__global__ __launch_bounds__(256) void k_bin(
    const int* __restrict__ src, const int* __restrict__ dst,
    int* __restrict__ gcur, unsigned int* __restrict__ packed)
{
    __shared__ unsigned int bins[256 * CAP_BIN];   // 64 KB
    __shared__ int cnt[256];
    const int tid = threadIdx.x;
    cnt[tid] = 0;
    __syncthreads();
    const int epb = (N_EDGES + gridDim.x - 1) / gridDim.x;
    int e0 = blockIdx.x * epb;
    int e1 = e0 + epb; if (e1 > N_EDGES) e1 = N_EDGES;
    for (int ch = e0; ch < e1; ch += 4096) {
        int chEnd = ch + 4096; if (chEnd > e1) chEnd = e1;
        for (int e = ch + tid; e < chEnd; e += 256) {
            int s = clampN(src[e]);
            int d = clampN(dst[e]);
            unsigned int val = (unsigned int)s | ((unsigned int)(d & 511) << 17);
            int b = d >> 9;
            int slot = atomicAdd(&cnt[b], 1);
            if (slot < CAP_BIN) bins[b * CAP_BIN + slot] = val;
            else {
                int g = atomicAdd(&gcur[b], 1);
                packed[g] = val;
            }
        }
        __syncthreads();
        int n = cnt[tid]; if (n > CAP_BIN) n = CAP_BIN;
        if (tid < NBUCK && n > 0) {
            int g = atomicAdd(&gcur[tid], n);
            for (int j = 0; j < n; ++j) packed[g + j] = bins[tid * CAP_BIN + j];
        }
        __syncthreads();
        cnt[tid] = 0;
        __syncthreads();
    }
}

__global__ __launch_bounds__(256) void k_bucket(
    const int* __restrict__ baseB, const unsigned int* __restrict__ packed,
    int* __restrict__ rowp, int* __restrict__ edge_src)
{
    __shared__ int hist[512], cur[512];
    __shared__ int wt[4];
    __shared__ unsigned int buf[CAP_B];            // 48 KB
    const int b = blockIdx.x, tid = threadIdx.x;
    const int lo = baseB[b], hi = baseB[b + 1], c = hi - lo;
    for (int i = tid; i < 512; i += 256) hist[i] = 0;
    __syncthreads();
    for (int e = tid; e < c; e += 256)
        atomicAdd(&hist[packed[lo + e] >> 17], 1);
    __syncthreads();
    int a0 = hist[2 * tid], a1 = hist[2 * tid + 1];
    int s = a0 + a1;
    int incl = s;
    #pragma unroll
    for (int off = 1; off < 64; off <<= 1) {
        int u = __shfl_up(incl, off);
        if ((tid & 63) >= off) incl += u;
    }
    if ((tid & 63) == 63) wt[tid >> 6] = incl;
    __syncthreads();
    int woff = 0;
    #pragma unroll
    for (int k = 0; k < 4; ++k) if (k < (tid >> 6)) woff += wt[k];
    int ep = woff + incl - s;
    cur[2 * tid] = ep;
    cur[2 * tid + 1] = ep + a0;
    int n0 = b * 512 + 2 * tid;
    if (n0 < N_NODES)     rowp[n0]     = lo + ep;
    if (n0 + 1 < N_NODES) rowp[n0 + 1] = lo + ep + a0;
    __syncthreads();
    for (int e = tid; e < c; e += 256) {
        unsigned int v = packed[lo + e];
        int dl = v >> 17;
        unsigned int sv = v & 0x1FFFFu;
        int pos = atomicAdd(&cur[dl], 1);
        if (pos < CAP_B) buf[pos] = sv;
        else edge_src[lo + pos] = (int)sv;
    }
    __syncthreads();
    int cc = c < CAP_B ? c : CAP_B;
    for (int e = tid; e < cc; e += 256) edge_src[lo + e] = (int)buf[e];
}

// ---------------- CSR mean-gather: one wave per node, 3-deep pipeline ----------------
// Both tables are [N][256] bf16.
// MODE 0: gather x-half (+128) of a2, write bf16 mean into agg-half (+0).
// MODE 1: gather t2-half (+0) of u2b, add own partial-half (+128), write f32 out.
template<int MODE>
__global__ __launch_bounds__(256) void k_gather16(
    const int* __restrict__ rp, const int* __restrict__ es,
    const __bf16* __restrict__ tab, void* __restrict__ outp)
{
    int wid = (blockIdx.x * 256 + threadIdx.x) >> 6;
    int l = threadIdx.x & 63;
    if (wid >= N_NODES) return;
    int start = rp[wid], end = rp[wid + 1];
    const int slot = l >> 4, c = l & 15;
    const size_t coff = (MODE == 0) ? (size_t)(128 + c * 8) : (size_t)(c * 8);
    float s0 = 0.f, s1 = 0.f, s2 = 0.f, s3 = 0.f;
    float s4 = 0.f, s5 = 0.f, s6 = 0.f, s7 = 0.f;

    int e0 = start + slot;
    int e1 = e0 + 4;
    int e2 = e1 + 4;
    bool h0 = e0 < end, h1 = e1 < end, h2 = e2 < end;
    v4u r0 = {0, 0, 0, 0}, r1 = {0, 0, 0, 0};
    if (h0) r0 = *(const v4u*)(tab + (size_t)es[e0] * 256 + coff);
    if (h1) r1 = *(const v4u*)(tab + (size_t)es[e1] * 256 + coff);
    int i2 = h2 ? es[e2] : 0;

    while (h0) {
        v4u r2 = {0, 0, 0, 0};
        if (h2) r2 = *(const v4u*)(tab + (size_t)i2 * 256 + coff);
        int e3 = e2 + 4;
        bool h3 = e3 < end;
        int i3 = h3 ? es[e3] : 0;
        s0 += bflo(r0.x); s1 += bfhi(r0.x);
        s2 += bflo(r0.y); s3 += bfhi(r0.y);
        s4 += bflo(r0.z); s5 += bfhi(r0.z);
        s6 += bflo(r0.w); s7 += bfhi(r0.w);
        r0 = r1; r1 = r2;
        h0 = h1; h1 = h2; h2 = h3;
        i2 = i3; e2 = e3;
    }

    s0 += __shfl_xor(s0, 16); s1 += __shfl_xor(s1, 16);
    s2 += __shfl_xor(s2, 16); s3 += __shfl_xor(s3, 16);
    s4 += __shfl_xor(s4, 16); s5 += __shfl_xor(s5, 16);
    s6 += __shfl_xor(s6, 16); s7 += __shfl_xor(s7, 16);
    s0 += __shfl_xor(s0, 32); s1 += __shfl_xor(s1, 32);
    s2 += __shfl_xor(s2, 32); s3 += __shfl_xor(s3, 32);
    s4 += __shfl_xor(s4, 32); s5 += __shfl_xor(s5, 32);
    s6 += __shfl_xor(s6, 32); s7 += __shfl_xor(s7, 32);
    float invd = 1.f / fmaxf((float)(end - start), 1.f);
    if (slot == 0) {
        if (MODE == 0) {
            PkU a, b, cc, d;
            a.h[0] = (__bf16)(s0 * invd); a.h[1] = (__bf16)(s1 * invd);
            b.h[0] = (__bf16)(s2 * invd); b.h[1] = (__bf16)(s3 * invd);
            cc.h[0] = (__bf16)(s4 * invd); cc.h[1] = (__bf16)(s5 * invd);
            d.h[0] = (__bf16)(s6 * invd); d.h[1] = (__bf16)(s7 * invd);
            v4u o = { a.u, b.u, cc.u, d.u };
            ((v4u*)outp)[(size_t)wid * 32 + c] = o;   // agg half of A'
        } else {
            // own partial (h@Wr2 + bl2 + p2, bf16) + gathered mean -> f32 out
            v4u pu = *(const v4u*)(tab + (size_t)wid * 256 + 128 + c * 8);
            float4 va, vb;
            va.x = s0 * invd + bflo(pu.x); va.y = s1 * invd + bfhi(pu.x);
            va.z = s2 * invd + bflo(pu.y); va.w = s3 * invd + bfhi(pu.y);
            vb.x = s4 * invd + bflo(pu.z); vb.y = s5 * invd + bfhi(pu.z);
            vb.z = s6 * invd + bflo(pu.w); vb.w = s7 * invd + bfhi(pu.w);
            ((float4*)outp)[(size_t)wid * 32 + c * 2]     = va;
            ((float4*)outp)[(size_t)wid * 32 + c * 2 + 1] = vb;
        }
    }
}

// ---------------- weight-stationary GEMM, persistent + pipelined ----------------
__device__ __forceinline__ void ld_stage(
    const __bf16* __restrict__ A, int tile, int tid, v4u st[4])
{
    const int row0 = tile * 64;
    #pragma unroll
    for (int cc = 0; cc < 4; ++cc) {
        int chunk = cc * 512 + tid;              // 2048 = 64 rows x 32 x 16B
        int row = chunk >> 5, col16 = chunk & 31;
        st[cc] = *(const v4u*)(A + (size_t)(row0 + row) * 256 + col16 * 8);
    }
}

// LAYER 1: outb = h (bf16 [N][256]) = A'@[Wl1;Wr1] + bl1 + p1
// LAYER 2: outb = u2b (bf16 [N][256]): cols 0-127 raw t2 = h@Wl2;
//          cols 128-255 partial = h@Wr2 + bl2 + p2
template<int LAYER>
__global__ __launch_bounds__(512, 2) void k_gws(
    const __bf16* __restrict__ A,
    const __bf16* __restrict__ WpA, const __bf16* __restrict__ WpB,
    const float* __restrict__ bias, const float* __restrict__ pert,
    __bf16* __restrict__ outb, int ntiles)
{
    __shared__ char aS[32768];
    __shared__ char hS[32768];
    const int tid = threadIdx.x;
    const int w = tid >> 6, l = tid & 63;
    const int lrow = l & 15, kg = l >> 4;
    const v4f zf = {0.f, 0.f, 0.f, 0.f};

    // resident B panel (per-wave columns)
    FragU bw[8][2];
    #pragma unroll
    for (int kc = 0; kc < 8; ++kc)
        #pragma unroll
        for (int nt = 0; nt < 2; ++nt) {
            const __bf16* Wp;
            int fi;
            if (LAYER == 1) {                // B' = [Wl1 ; Wr1] K-concat, NT=16
                Wp = (kc < 4) ? WpA : WpB;
                fi = (kc & 3) * 16 + w * 2 + nt;
            } else {                         // B'' = [Wl2 | Wr2] N-concat, NT=8
                Wp = (w < 4) ? WpA : WpB;
                fi = kc * 8 + (w & 3) * 2 + nt;
            }
            bw[kc][nt].u = *(const v4u*)(Wp + ((size_t)fi * 64 + l) * 8);
        }

    int tile = blockIdx.x;
    v4u st[4];
    if (tile < ntiles) ld_stage(A, tile, tid, st);

    for (; tile < ntiles; tile += gridDim.x) {
        #pragma unroll
        for (int cc = 0; cc < 4; ++cc) {
            int chunk = cc * 512 + tid;
            int row = chunk >> 5, col16 = chunk & 31;
            int byte = (row * 512 + col16 * 16) ^ ((row & 7) << 4);
            *(v4u*)(aS + byte) = st[cc];
        }
        int nxt = tile + (int)gridDim.x;
        if (nxt < ntiles) ld_stage(A, nxt, tid, st);   // in flight across compute
        __syncthreads();                               // B_a

        const int row0 = tile * 64;
        #pragma unroll
        for (int rf = 0; rf < 4; ++rf) {
            const int arow = rf * 16 + lrow;
            FragU a[8];
            #pragma unroll
            for (int kc = 0; kc < 8; ++kc) {
                int byte = arow * 512 + ((kc * 64 + kg * 16) ^ ((arow & 7) << 4));
                a[kc].u = *(const v4u*)(aS + byte);
            }
            v4f acc[2] = {zf, zf};
            #pragma unroll
            for (int kc = 0; kc < 8; ++kc) {
                acc[0] = __builtin_amdgcn_mfma_f32_16x16x32_bf16(a[kc].b, bw[kc][0].b, acc[0], 0, 0, 0);
                acc[1] = __builtin_amdgcn_mfma_f32_16x16x32_bf16(a[kc].b, bw[kc][1].b, acc[1], 0, 0, 0);
            }
            #pragma unroll
            for (int nt = 0; nt < 2; ++nt)
                #pragma unroll
                for (int r = 0; r < 4; ++r) {
                    int row = rf * 16 + kg * 4 + r;
                    int col = w * 32 + nt * 16 + lrow;
                    int byte = (row * 512 + col * 2) ^ ((row & 7) << 4);
                    *(__bf16*)(hS + byte) = (__bf16)acc[nt][r];
                }
        }
        __syncthreads();                               // B_h

        // coalesced epilogue: each wave-iter covers one full 512B row
        #pragma unroll
        for (int it = 0; it < 8; ++it) {
            int chunk = it * 512 + tid;                // 4096 = 64 rows x 64 x 8B
            int row = chunk >> 6, c4 = chunk & 63;
            int grow = row0 + row;
            if (grow >= N_NODES) continue;
            int byte = (row * 512 + c4 * 8) ^ ((row & 7) << 4);
            Pk2 pk; pk.u2 = *(const uint2*)(hS + byte);
            if (LAYER == 1) {
                float4 pv = ((const float4*)pert)[(size_t)grow * 64 + c4];
                float4 bv = ((const float4*)bias)[c4];
                PkU o0, o1;
                o0.h[0] = (__bf16)((float)pk.h[0] + pv.x + bv.x);
                o0.h[1] = (__bf16)((float)pk.h[1] + pv.y + bv.y);
                o1.h[0] = (__bf16)((float)pk.h[2] + pv.z + bv.z);
                o1.h[1] = (__bf16)((float)pk.h[3] + pv.w + bv.w);
                uint2 ov = { o0.u, o1.u };
                *(uint2*)(outb + (size_t)grow * 256 + c4 * 4) = ov;
            } else {
                uint2 ov;
                if (c4 < 32) {
                    ov = pk.u2;                         // raw t2 half
                } else {
                    int oc4 = c4 - 32;                  // partial half + bias + pert
                    float4 pv = ((const float4*)pert)[(size_t)grow * 32 + oc4];
                    float4 bv = ((const float4*)bias)[oc4];
                    PkU o0, o1;
                    o0.h[0] = (__bf16)((float)pk.h[0] + pv.x + bv.x);
                    o0.h[1] = (__bf16)((float)pk.h[1] + pv.y + bv.y);
                    o1.h[0] = (__bf16)((float)pk.h[2] + pv.z + bv.z);
                    o1.h[1] = (__bf16)((float)pk.h[3] + pv.w + bv.w);
                    ov.x = o0.u; ov.y = o1.u;
                }
                *(uint2*)(outb + (size_t)grow * 256 + c4 * 4) = ov;
            }
        }
    }
}

extern "C" void kernel_launch(void* const* d_in, const int* in_sizes, int n_in,
                              void* d_out, int out_size, void* d_ws, size_t ws_size,
                              hipStream_t stream)
{
    const float* x   = (const float*)d_in[0];
    const int*   ei  = (const int*)d_in[1];
    const float* p1  = (const float*)d_in[2];
    const float* p2  = (const float*)d_in[3];
    const float* Wl1 = (const float*)d_in[4];
    const float* bl1 = (const float*)d_in[5];
    const float* Wr1 = (const float*)d_in[6];
    const float* Wl2 = (const float*)d_in[7];
    const float* bl2 = (const float*)d_in[8];
    const float* Wr2 = (const float*)d_in[9];
    const int* src = ei;
    const int* dst = ei + N_EDGES;

    const size_t NPAD = (size_t)N_NODES + 64;
    char* wp = (char*)d_ws;
    __bf16* a2   = (__bf16*)wp; wp += NPAD * 256 * 2;   // A' = [agg | x]
    __bf16* hb   = (__bf16*)wp; wp += NPAD * 256 * 2;   // h
    __bf16* u2b  = (__bf16*)wp; wp += NPAD * 256 * 2;   // [t2 | partial]
    __bf16* Wl1p = (__bf16*)wp; wp += 128 * 256 * 2;
    __bf16* Wr1p = (__bf16*)wp; wp += 128 * 256 * 2;
    __bf16* Wl2p = (__bf16*)wp; wp += 256 * 128 * 2;
    __bf16* Wr2p = (__bf16*)wp; wp += 256 * 128 * 2;
    int* bucketCnt = (int*)wp; wp += 512 * 4;
    int* baseB     = (int*)wp; wp += 512 * 4;
    int* gcur      = (int*)wp; wp += 512 * 4;
    int* rowp      = (int*)wp; wp += (size_t)(N_NODES + 1) * 4 + 12;
    unsigned int* packed = (unsigned int*)wp; wp += (size_t)N_EDGES * 4;
    int* es        = (int*)wp;

    hipMemsetAsync(bucketCnt, 0, 512 * 4, stream);

    const int gblocks = (N_NODES * 64 + 255) / 256;
    const int tiles = (N_NODES + 63) / 64;
    const int prep_blocks = CVT_BLKS + 64 + (N_EDGES + 4095) / 4096;  // 12955

    k_prep<<<prep_blocks, 256, 0, stream>>>(
        x, a2, Wl1, Wr1, Wl2, Wr2, Wl1p, Wr1p, Wl2p, Wr2p, dst, bucketCnt);
    k_scanb<<<1, 256, 0, stream>>>(bucketCnt, baseB, gcur, rowp);
    k_bin<<<256, 256, 0, stream>>>(src, dst, gcur, packed);
    k_bucket<<<NBUCK, 256, 0, stream>>>(baseB, packed, rowp, es);

    k_gather16<0><<<gblocks, 256, 0, stream>>>(rowp, es, a2, a2);
    k_gws<1><<<512, 512, 0, stream>>>(a2, Wl1p, Wr1p, bl1, p1, hb, tiles);
    k_gws<2><<<512, 512, 0, stream>>>(hb, Wl2p, Wr2p, bl2, p2, u2b, tiles);
    k_gather16<1><<<gblocks, 256, 0, stream>>>(rowp, es, u2b, (void*)d_out);
}